// Round 6
// baseline (370.218 us; speedup 1.0000x reference)
//
#include <hip/hip_runtime.h>
#include <math.h>

#define Bsz 4
#define DIM 512
#define LEN 4096
#define DST 16
#define DIN 1024
#define NCH 64    // chunks over L
#define CHL 64    // chunk length

typedef unsigned short ushort_t;
typedef unsigned int uint_t;
typedef __attribute__((ext_vector_type(8))) short short8;          // 8 bf16 (4 VGPRs)
typedef __attribute__((ext_vector_type(8))) unsigned short ushort8;
typedef __attribute__((ext_vector_type(8))) _Float16 half8;        // 8 fp16
typedef __attribute__((ext_vector_type(4))) float f32x4;

__device__ __forceinline__ float sigmoidf_(float x){ return 1.0f/(1.0f+__expf(-x)); }
__device__ __forceinline__ float bf2f(ushort_t u){ return __uint_as_float(((uint_t)u) << 16); }
__device__ __forceinline__ ushort_t f2bf(float f){
  uint_t x = __float_as_uint(f);
  uint_t r = (x + 0x7FFFu + ((x >> 16) & 1u)) >> 16;
  return (ushort_t)r;
}
__device__ __forceinline__ ushort_t f2h_bits(float f){
  _Float16 h = (_Float16)f;
  union { _Float16 h; ushort_t u; } v; v.h = h; return v.u;
}
__device__ __forceinline__ void gl2lds16(const void* g, void* l){
  __builtin_amdgcn_global_load_lds((const __attribute__((address_space(1))) void*)g,
                                   (__attribute__((address_space(3))) void*)l, 16, 0, 0);
}
// a^1..a^16 from a1=exp(-dv), log-depth
#define POW_CHAIN(av, a1) \
  { float a2=a1*a1, a4=a2*a2, a8=a4*a4; \
    av[0]=a1; av[1]=a2; av[2]=a2*a1; av[3]=a4; \
    av[4]=a4*a1; av[5]=a4*a2; av[6]=a4*av[2]; av[7]=a8; \
    av[8]=a8*a1; av[9]=a8*a2; av[10]=a8*av[2]; av[11]=a8*a4; \
    av[12]=a8*av[4]; av[13]=a8*av[5]; av[14]=a8*av[6]; av[15]=a8*a8; }

__device__ __forceinline__ bool load_nA(const float* Alog, int d, float* nA){
  bool fast = true;
  #pragma unroll
  for(int s=0;s<DST;s++){
    float v = -__expf(Alog[d*DST+s]);
    float tgt = -(float)(s+1);
    if(fabsf(v - tgt) < 1e-4f*(float)(s+1)) v = tgt;
    else fast = false;
    nA[s] = v;
  }
  return fast;
}

// ---------------- LayerNorm stats ----------------
__global__ __launch_bounds__(256) void ln_stats_k(const float* __restrict__ x,
                                                  float* __restrict__ mu, float* __restrict__ rs){
  int bid = blockIdx.x;
  int b = bid >> 6;
  int lg = bid & 63;
  int lane = threadIdx.x & 63;
  int g = threadIdx.x >> 6;
  int l = lg*64 + lane;
  const float* xb = x + (size_t)b*DIM*LEN + l;
  float s = 0.f, sq = 0.f;
  for(int d = g*128; d < g*128 + 128; ++d){
    float v = xb[(size_t)d*LEN];
    s += v; sq += v*v;
  }
  __shared__ float rsum[4][64], rsq[4][64];
  rsum[g][lane] = s; rsq[g][lane] = sq;
  __syncthreads();
  if(threadIdx.x < 64){
    float ts = 0.f, tq = 0.f;
    for(int gg=0; gg<4; ++gg){ ts += rsum[gg][lane]; tq += rsq[gg][lane]; }
    float m = ts * (1.0f/DIM);
    float var = tq * (1.0f/DIM) - m*m;
    mu[b*LEN + l] = m;
    rs[b*LEN + l] = rsqrtf(var + 1e-5f);
  }
}

// ---------------- weights -> bf16 ----------------
__global__ __launch_bounds__(256) void wcvt_k(const float* __restrict__ Win,
    const float* __restrict__ Wout, const float* __restrict__ Wxp,
    ushort_t* __restrict__ Winb, ushort_t* __restrict__ Woutb, ushort_t* __restrict__ Wxpb){
  int i = blockIdx.x*256 + threadIdx.x;   // 1,638,400 total
  if(i < 1048576) Winb[i] = f2bf(Win[i]);
  else if(i < 1572864) Woutb[i-1048576] = f2bf(Wout[i-1048576]);
  else if(i < 1638400) Wxpb[i-1572864] = f2bf(Wxp[i-1572864]);
}

// ---------------- LN apply + transpose -> xnT bf16 [B*L][512] ----------------
__global__ __launch_bounds__(256) void xnt_k(const float* __restrict__ x,
    const float* __restrict__ mu, const float* __restrict__ rs,
    const float* __restrict__ lnw, const float* __restrict__ lnb, ushort_t* __restrict__ xnT){
  __shared__ ushort_t t[64][72];
  int bid = blockIdx.x;              // 4 * 8 * 64 = 2048
  int lt = bid & 63;
  int dt_ = (bid >> 6) & 7;
  int b = bid >> 9;
  int l0 = lt*64, d0 = dt_*64;
  int ll = threadIdx.x & 63;
  int dq = threadIdx.x >> 6;
  float mul_ = mu[b*LEN + l0 + ll], rsl = rs[b*LEN + l0 + ll];
  const float* xb = x + (size_t)b*DIM*LEN;
  #pragma unroll
  for(int i=0;i<16;i++){
    int d = d0 + dq*16 + i;
    float v = xb[(size_t)d*LEN + l0 + ll];
    t[ll][dq*16 + i] = f2bf((v - mul_)*rsl*lnw[d] + lnb[d]);
  }
  __syncthreads();
  int lr = threadIdx.x >> 2, seg = threadIdx.x & 3;
  ushort_t* dst = &xnT[(size_t)(b*LEN + l0 + lr)*DIM + d0 + seg*16];
  #pragma unroll
  for(int k=0;k<4;k++){
    ushort4 v = *(const ushort4*)&t[lr][seg*16 + k*4];
    *(ushort4*)&dst[k*4] = v;
  }
}

// ---------------- GEMM1 MFMA v7: 256x128 tile, 8 waves, 3-buffer ring, distance-2 prefetch ----
// xnT[16384][512] x Winb[2048][512] -> xin fp16 (n<1024) / sz bf16 (n>=1024)
// At iter kt: stage kt+2; vmcnt(12) waits only kt's 6 loads (issued 2 compute-phases ago,
// ~full HBM latency hidden); kt+1/kt+2 loads stay in flight across the barrier.
// LDS XOR-swizzle (chunk' = chunk ^ (row&7)) via pre-swizzled global source; same XOR on read.
__global__ __launch_bounds__(512) void gemm1_mfma(const ushort_t* __restrict__ A,
    const ushort_t* __restrict__ Bw, _Float16* __restrict__ xin, ushort_t* __restrict__ sz){
  __shared__ __align__(16) ushort_t smem[3*24576];   // 3 x (A 32KB + B 16KB) = 147,456 B
  int tid = threadIdx.x;
  int wave = tid >> 6, lane = tid & 63;
  // XCD swizzle: 1024 blocks -> 128 contiguous tiles per XCD (1024 % 8 == 0, bijective)
  int flat = blockIdx.x;
  int orig = (flat & 7) * 128 + (flat >> 3);
  int n0 = (orig & 15) * 128;      // 16 n-tiles
  int m0 = (orig >> 4) * 256;      // 64 m-tiles
  int wm = (wave >> 1) * 64, wn = (wave & 1) * 64;   // per-wave 64x64
  int lm = lane & 15;
  int lk = lane >> 4;
  int sx = lm & 7;
  f32x4 zero4 = {0.f,0.f,0.f,0.f};
  f32x4 acc[4][4];
  #pragma unroll
  for(int i=0;i<4;i++)
    #pragma unroll
    for(int j=0;j<4;j++) acc[i][j] = zero4;

  auto STAGE = [&](int kt, int bi){
    int k0 = kt*64;
    ushort_t* As = &smem[bi*24576];
    ushort_t* Bs = &smem[bi*24576 + 16384];
    #pragma unroll
    for(int i=0;i<4;i++){
      int c = i*512 + tid, r = c >> 3, kc = c & 7;
      int kg = kc ^ (r & 7);
      gl2lds16(&A[(size_t)(m0 + r)*512 + k0 + kg*8], &As[c*8]);
    }
    #pragma unroll
    for(int i=0;i<2;i++){
      int c = i*512 + tid, r = c >> 3, kc = c & 7;
      int kg = kc ^ (r & 7);
      gl2lds16(&Bw[(size_t)(n0 + r)*512 + k0 + kg*8], &Bs[c*8]);
    }
  };

  STAGE(0, 0);
  STAGE(1, 1);
  for(int kt=0; kt<8; ++kt){
    int bi = kt % 3;
    if(kt + 2 < 8) STAGE(kt+2, (kt+2) % 3);
    if(kt < 6)       asm volatile("s_waitcnt vmcnt(12)" ::: "memory");
    else if(kt == 6) asm volatile("s_waitcnt vmcnt(6)"  ::: "memory");
    else             asm volatile("s_waitcnt vmcnt(0)"  ::: "memory");
    __builtin_amdgcn_sched_barrier(0);
    __builtin_amdgcn_s_barrier();
    const ushort_t* As = &smem[bi*24576];
    const ushort_t* Bs = &smem[bi*24576 + 16384];
    #pragma unroll
    for(int kk=0; kk<64; kk+=32){
      short8 af[4], bf[4];
      int ch = ((kk >> 3) + lk) ^ sx;
      #pragma unroll
      for(int i=0;i<4;i++){
        af[i] = *(const short8*)&As[(wm + i*16 + lm)*64 + ch*8];
        bf[i] = *(const short8*)&Bs[(wn + i*16 + lm)*64 + ch*8];
      }
      #pragma unroll
      for(int i=0;i<4;i++)
        #pragma unroll
        for(int j=0;j<4;j++)
          acc[i][j] = __builtin_amdgcn_mfma_f32_16x16x32_bf16(af[i], bf[j], acc[i][j], 0, 0, 0);
    }
    __builtin_amdgcn_s_barrier();   // readers done before next iter's STAGE reuses this buffer
  }
  // epilogue: two m-halves of 128; LDS transpose (ushort [128][136]) + coalesced 16B stores
  ushort_t* T = smem;                      // 17,408 ushorts
  bool is_z = (n0 >= 1024);
  for(int h=0; h<2; ++h){
    __syncthreads();
    if((wave >> 2) == h){
      #pragma unroll
      for(int i=0;i<4;i++)
        #pragma unroll
        for(int j=0;j<4;j++)
          #pragma unroll
          for(int r=0;r<4;r++){
            int ml = (wm - h*128) + i*16 + lk*4 + r;   // 0..127 within half
            int nl = wn + j*16 + lm;                   // 0..127
            float v = acc[i][j][r];
            T[ml*136 + nl] = is_z ? f2bf(v * sigmoidf_(v)) : f2h_bits(v);
          }
    }
    __syncthreads();
    int rr = tid >> 4, cc = (tid & 15)*8;   // rr 0..31, cc 0..120
    #pragma unroll
    for(int p=0;p<4;p++){
      int row = p*32 + rr;
      ushort8 v = *(const ushort8*)&T[row*136 + cc];
      int gm = m0 + h*128 + row;
      if(!is_z) *(ushort8*)((ushort_t*)xin + (size_t)gm*DIN + n0 + cc) = v;
      else      *(ushort8*)&sz[(size_t)gm*DIN + (n0-1024) + cc] = v;
    }
  }
}

// ---------------- conv1d + SiLU -> u bf16 (streaming: 8 d x 8 l per thread) ----------------
__global__ __launch_bounds__(256) void conv_silu_k(const _Float16* __restrict__ xin,
    const float* __restrict__ cw, const float* __restrict__ cb, ushort_t* __restrict__ u){
  int idx = blockIdx.x*256 + threadIdx.x;   // 262,144 threads: (b, lc, dg)
  int dg = idx & 127;
  int lc = (idx >> 7) & 511;                // 512 chunks of 8 l
  int b  = idx >> 16;
  int d0 = dg*8;
  int l0 = lc*8;
  float bias[8];
  #pragma unroll
  for(int k=0;k<8;k+=4){
    float4 c4 = *(const float4*)&cb[d0+k];
    bias[k]=c4.x; bias[k+1]=c4.y; bias[k+2]=c4.z; bias[k+3]=c4.w;
  }
  float w[8][4];
  #pragma unroll
  for(int k=0;k<8;k++){
    float4 c4 = *(const float4*)&cw[(d0+k)*4];
    w[k][0]=c4.x; w[k][1]=c4.y; w[k][2]=c4.z; w[k][3]=c4.w;
  }
  const _Float16* base = xin + ((size_t)b*LEN)*DIN + d0;
  ushort_t* ub = u + ((size_t)b*LEN)*DIN + d0;
  float f0[8], f1[8], f2[8];
  if(lc > 0){
    half8 h0 = *(const half8*)&base[(size_t)(l0-3)*DIN];
    half8 h1 = *(const half8*)&base[(size_t)(l0-2)*DIN];
    half8 h2 = *(const half8*)&base[(size_t)(l0-1)*DIN];
    #pragma unroll
    for(int k=0;k<8;k++){ f0[k]=(float)h0[k]; f1[k]=(float)h1[k]; f2[k]=(float)h2[k]; }
  } else {
    #pragma unroll
    for(int k=0;k<8;k++){ f0[k]=0.f; f1[k]=0.f; f2[k]=0.f; }
  }
  #pragma unroll
  for(int t=0;t<8;t++){
    half8 xv = *(const half8*)&base[(size_t)(l0+t)*DIN];
    float f3[8];
    #pragma unroll
    for(int k=0;k<8;k++) f3[k] = (float)xv[k];
    short8 o;
    #pragma unroll
    for(int k=0;k<8;k++){
      float a = bias[k] + f0[k]*w[k][0] + f1[k]*w[k][1] + f2[k]*w[k][2] + f3[k]*w[k][3];
      float v = a * sigmoidf_(a);
      o[k] = (short)f2bf(v);
    }
    *(short8*)&ub[(size_t)(l0+t)*DIN] = o;
    #pragma unroll
    for(int k=0;k<8;k++){ f0[k]=f1[k]; f1[k]=f2[k]; f2[k]=f3[k]; }
  }
}

// ---------------- GEMM2 MFMA v3: BM=64 (256 blocks, full CU coverage) + counted vmcnt ----------
// u[16384][1024] x Wxpb[64][1024] -> dbl fp32 [16384][64]
__global__ __launch_bounds__(256) void gemm2_mfma(const ushort_t* __restrict__ A,
    const ushort_t* __restrict__ Bw, float* __restrict__ dbl){
  __shared__ __align__(16) ushort_t smem[2*8192];   // 2 bufs x (As 4096 + Bs 4096) = 32 KiB
  int tid = threadIdx.x;
  int wave = tid >> 6, lane = tid & 63;
  int m0 = blockIdx.x * 64;
  int wm = (wave >> 1) * 32, wn = (wave & 1) * 32;
  int lm = lane & 15;
  int lk = lane >> 4;
  int sx = lm & 7;
  f32x4 zero4 = {0.f,0.f,0.f,0.f};
  f32x4 acc[2][2];
  #pragma unroll
  for(int i=0;i<2;i++){ acc[i][0] = zero4; acc[i][1] = zero4; }
  // prologue: stage t=0 into buf 0
  #pragma unroll
  for(int i=0;i<2;i++){
    int c = i*256 + tid, r = c >> 3, kc = c & 7;
    int kg = kc ^ (r & 7);
    gl2lds16(&A [(size_t)(m0 + r)*1024 + kg*8], &smem[c*8]);
    gl2lds16(&Bw[(size_t)r*1024 + kg*8], &smem[4096 + c*8]);
  }
  int cur = 0;
  for(int t=0; t<16; ++t){
    if(t < 15){
      int k0n = (t+1)*64;
      ushort_t* Ad = &smem[(cur^1)*8192];
      ushort_t* Bd = &smem[(cur^1)*8192 + 4096];
      #pragma unroll
      for(int i=0;i<2;i++){
        int c = i*256 + tid, r = c >> 3, kc = c & 7;
        int kg = kc ^ (r & 7);
        gl2lds16(&A [(size_t)(m0 + r)*1024 + k0n + kg*8], &Ad[c*8]);
        gl2lds16(&Bw[(size_t)r*1024 + k0n + kg*8], &Bd[c*8]);
      }
      asm volatile("s_waitcnt vmcnt(4)" ::: "memory");
    } else {
      asm volatile("s_waitcnt vmcnt(0)" ::: "memory");
    }
    __builtin_amdgcn_sched_barrier(0);
    __builtin_amdgcn_s_barrier();
    const ushort_t* As = &smem[cur*8192];
    const ushort_t* Bs = &smem[cur*8192 + 4096];
    #pragma unroll
    for(int kk=0; kk<64; kk+=32){
      short8 af[2], bf[2];
      int ch = ((kk >> 3) + lk) ^ sx;
      #pragma unroll
      for(int i=0;i<2;i++) af[i] = *(const short8*)&As[(wm + i*16 + lm)*64 + ch*8];
      #pragma unroll
      for(int j=0;j<2;j++) bf[j] = *(const short8*)&Bs[(wn + j*16 + lm)*64 + ch*8];
      #pragma unroll
      for(int i=0;i<2;i++)
        #pragma unroll
        for(int j=0;j<2;j++)
          acc[i][j] = __builtin_amdgcn_mfma_f32_16x16x32_bf16(af[i], bf[j], acc[i][j], 0, 0, 0);
    }
    __builtin_amdgcn_s_barrier();
    cur ^= 1;
  }
  #pragma unroll
  for(int i=0;i<2;i++)
    #pragma unroll
    for(int j=0;j<2;j++)
      #pragma unroll
      for(int r=0;r<4;r++){
        int m = m0 + wm + i*16 + lk*4 + r;
        int n = wn + j*16 + lm;
        dbl[(size_t)m*64 + n] = acc[i][j][r];
      }
}

// ---------------- deltag: dv[m,d] = softplus(dbl[m,0:32]·Wdt[d,:]+bdt[d]) -> fp16 ----------------
__global__ __launch_bounds__(256,4) void deltag_k(const float* __restrict__ dbl,
    const float* __restrict__ Wdt, const float* __restrict__ bdt,
    _Float16* __restrict__ dF){
  __shared__ __align__(16) float dts[64*32];
  int bid = blockIdx.x;              // 256 m-tiles x 4 d-tiles = 1024
  int d0 = (bid & 3) * 256;
  int m0 = (bid >> 2) * 64;
  int tid = threadIdx.x;
  const f32x4* src4 = (const f32x4*)(dbl + (size_t)m0*64);
  f32x4* dst4 = (f32x4*)dts;
  for(int i=tid; i<64*8; i+=256){
    int row = i >> 3, q = i & 7;
    dst4[i] = src4[row*16 + q];
  }
  int d = d0 + tid;
  float w[32];
  #pragma unroll
  for(int k=0;k<32;k+=4){
    float4 t4 = *(const float4*)&Wdt[d*32+k];
    w[k]=t4.x; w[k+1]=t4.y; w[k+2]=t4.z; w[k+3]=t4.w;
  }
  float bd = bdt[d];
  __syncthreads();
  for(int m=0;m<64;m++){
    const float* row = dts + m*32;
    float dtv = bd;
    #pragma unroll
    for(int k=0;k<32;k+=4){
      f32x4 q = *(const f32x4*)&row[k];
      dtv += q.x*w[k] + q.y*w[k+1] + q.z*w[k+2] + q.w*w[k+3];
    }
    float dv = dtv > 15.f ? dtv : __logf(1.f + __expf(dtv));
    dF[(size_t)(m0+m)*DIN + d] = (_Float16)dv;
  }
}

// ---------------- scan phase A: per-chunk local end state + cumD ----------------
__global__ __launch_bounds__(256,4) void scanA_k(const ushort_t* __restrict__ u,
    const float* __restrict__ dbl, const float* __restrict__ Alog,
    const _Float16* __restrict__ dF,
    float* __restrict__ E, float* __restrict__ cum){
  __shared__ __align__(16) float dch[CHL*16];   // B cols
  int bid = blockIdx.x;            // NCH*4*Bsz = 1024
  int c = bid & (NCH-1);
  int dblk = (bid >> 6) & 3;
  int b = bid >> 8;
  int d = dblk*256 + threadIdx.x;
  const f32x4* src = (const f32x4*)(dbl + ((size_t)b*LEN + c*CHL)*64);
  f32x4* dst4 = (f32x4*)dch;
  for(int i=threadIdx.x; i<CHL*4; i+=256){
    int t = i >> 2, q = i & 3;
    dst4[i] = src[t*16 + 8 + q];
  }
  float nA[DST];
  bool fast = load_nA(Alog, d, nA);
  float Es[DST];
  #pragma unroll
  for(int s=0;s<DST;s++) Es[s] = 0.f;
  float cumD = 0.f;
  __syncthreads();
  const ushort_t*  uu = u  + ((size_t)b*LEN + c*CHL)*DIN + d;
  const _Float16*  pd = dF + ((size_t)b*LEN + c*CHL)*DIN + d;
  if(fast){
    for(int t=0;t<CHL;++t){
      float dv = (float)pd[(size_t)t*DIN];
      float uv = bf2f(uu[(size_t)t*DIN]);
      float du = dv*uv;
      cumD += dv;
      float a1 = __expf(-dv);
      float av[DST];
      POW_CHAIN(av, a1);
      const f32x4* r4 = (const f32x4*)(dch + t*16);
      f32x4 B0=r4[0], B1=r4[1], B2=r4[2], B3=r4[3];
      Es[0]=av[0]*Es[0]+du*B0.x;  Es[1]=av[1]*Es[1]+du*B0.y;
      Es[2]=av[2]*Es[2]+du*B0.z;  Es[3]=av[3]*Es[3]+du*B0.w;
      Es[4]=av[4]*Es[4]+du*B1.x;  Es[5]=av[5]*Es[5]+du*B1.y;
      Es[6]=av[6]*Es[6]+du*B1.z;  Es[7]=av[7]*Es[7]+du*B1.w;
      Es[8]=av[8]*Es[8]+du*B2.x;  Es[9]=av[9]*Es[9]+du*B2.y;
      Es[10]=av[10]*Es[10]+du*B2.z; Es[11]=av[11]*Es[11]+du*B2.w;
      Es[12]=av[12]*Es[12]+du*B3.x; Es[13]=av[13]*Es[13]+du*B3.y;
      Es[14]=av[14]*Es[14]+du*B3.z; Es[15]=av[15]*Es[15]+du*B3.w;
    }
  } else {
    for(int t=0;t<CHL;++t){
      float dv = (float)pd[(size_t)t*DIN];
      float uv = bf2f(uu[(size_t)t*DIN]);
      float du = dv*uv;
      cumD += dv;
      const float* row = dch + t*16;
      #pragma unroll
      for(int s=0;s<DST;s++){
        float a = __expf(dv*nA[s]);
        Es[s] = a*Es[s] + du*row[s];
      }
    }
  }
  size_t o = (size_t)(b*NCH + c)*DST*DIN + d;
  #pragma unroll
  for(int s=0;s<DST;s++) E[o + (size_t)s*DIN] = Es[s];
  cum[(size_t)(b*NCH + c)*DIN + d] = cumD;
}

// ---------------- scan phase B: combine chunk boundaries; Hs in-place over E ----------------
__global__ __launch_bounds__(256) void scanB_k(const float* __restrict__ cum,
    const float* __restrict__ Alog, float* __restrict__ E){
  int g = blockIdx.x*256 + threadIdx.x;   // 65536 = Bsz*DST*DIN
  int d = g & 1023;
  int s = (g >> 10) & 15;
  int b = g >> 14;
  float v = -__expf(Alog[d*DST + s]);
  float tgt = -(float)(s+1);
  float nA = (fabsf(v - tgt) < 1e-4f*(float)(s+1)) ? tgt : v;
  float h = 0.f;
  for(int c=0;c<NCH;c++){
    float p = __expf(cum[(size_t)(b*NCH + c)*DIN + d] * nA);
    size_t o = (size_t)((b*NCH + c)*DST + s)*DIN + d;
    float e = E[o];
    E[o] = h;
    h = p*h + e;
  }
}

// ---------------- scan phase C: replay, y=(scan+u*D)*sz, y bf16 over u ----------------
__global__ __launch_bounds__(256,4) void scanC_k(ushort_t* __restrict__ u,
    const float* __restrict__ dbl, const float* __restrict__ Alog,
    const float* __restrict__ Hs, const float* __restrict__ Dp, const ushort_t* __restrict__ sz,
    const _Float16* __restrict__ dF){
  __shared__ __align__(16) float dch[CHL*32];   // B,C cols
  int bid = blockIdx.x;
  int c = bid & (NCH-1);
  int dblk = (bid >> 6) & 3;
  int b = bid >> 8;
  int d = dblk*256 + threadIdx.x;
  const f32x4* src = (const f32x4*)(dbl + ((size_t)b*LEN + c*CHL)*64);
  f32x4* dst4 = (f32x4*)dch;
  for(int i=threadIdx.x; i<CHL*8; i+=256){
    int t = i >> 3, q = i & 7;
    dst4[i] = src[t*16 + 8 + q];
  }
  float nA[DST];
  bool fast = load_nA(Alog, d, nA);
  float h[DST];
  size_t ho = (size_t)(b*NCH + c)*DST*DIN + d;
  #pragma unroll
  for(int s=0;s<DST;s++) h[s] = Hs[ho + (size_t)s*DIN];
  float Dv = Dp[d];
  __syncthreads();
  ushort_t* uu = u + ((size_t)b*LEN + c*CHL)*DIN + d;
  const ushort_t* zz = sz + ((size_t)b*LEN + c*CHL)*DIN + d;
  const _Float16* pd = dF + ((size_t)b*LEN + c*CHL)*DIN + d;
  if(fast){
    for(int t=0;t<CHL;++t){
      float dv = (float)pd[(size_t)t*DIN];
      float uv = bf2f(uu[(size_t)t*DIN]);
      float du = dv*uv;
      float a1 = __expf(-dv);
      float av[DST];
      POW_CHAIN(av, a1);
      const f32x4* r4 = (const f32x4*)(dch + t*32);
      f32x4 B0=r4[0], B1=r4[1], B2=r4[2], B3=r4[3];
      f32x4 C0=r4[4], C1=r4[5], C2=r4[6], C3=r4[7];
      float y0, y1, y2, y3;
      h[0]=av[0]*h[0]+du*B0.x;  h[1]=av[1]*h[1]+du*B0.y;
      h[2]=av[2]*h[2]+du*B0.z;  h[3]=av[3]*h[3]+du*B0.w;
      y0 = h[0]*C0.x + h[1]*C0.y; y1 = h[2]*C0.z + h[3]*C0.w;
      h[4]=av[4]*h[4]+du*B1.x;  h[5]=av[5]*h[5]+du*B1.y;
      h[6]=av[6]*h[6]+du*B1.z;  h[7]=av[7]*h[7]+du*B1.w;
      y2 = h[4]*C1.x + h[5]*C1.y; y3 = h[6]*C1.z + h[7]*C1.w;
      h[8]=av[8]*h[8]+du*B2.x;  h[9]=av[9]*h[9]+du*B2.y;
      h[10]=av[10]*h[10]+du*B2.z; h[11]=av[11]*h[11]+du*B2.w;
      y0 += h[8]*C2.x + h[9]*C2.y; y1 += h[10]*C2.z + h[11]*C2.w;
      h[12]=av[12]*h[12]+du*B3.x; h[13]=av[13]*h[13]+du*B3.y;
      h[14]=av[14]*h[14]+du*B3.z; h[15]=av[15]*h[15]+du*B3.w;
      y2 += h[12]*C3.x + h[13]*C3.y; y3 += h[14]*C3.z + h[15]*C3.w;
      float y = (y0+y1) + (y2+y3) + uv*Dv;
      y *= bf2f(zz[(size_t)t*DIN]);
      uu[(size_t)t*DIN] = f2bf(y);
    }
  } else {
    for(int t=0;t<CHL;++t){
      float dv = (float)pd[(size_t)t*DIN];
      float uv = bf2f(uu[(size_t)t*DIN]);
      float du = dv*uv;
      const float* row = dch + t*32;
      float y = 0.f;
      #pragma unroll
      for(int s=0;s<DST;s++){
        float a = __expf(dv*nA[s]);
        h[s] = a*h[s] + du*row[s];
        y += h[s]*row[16+s];
      }
      y += uv*Dv;
      y *= bf2f(zz[(size_t)t*DIN]);
      uu[(size_t)t*DIN] = f2bf(y);
    }
  }
}

// ---------------- GEMM4 MFMA v7: 256x128 tile, 8 waves, 3-buffer ring, distance-2 prefetch ----
// y[16384][1024] x Woutb[512][1024] -> out[b][n][l]
__global__ __launch_bounds__(512) void gemm4_mfma(const ushort_t* __restrict__ A,
    const ushort_t* __restrict__ Bw, float* __restrict__ out){
  __shared__ __align__(16) ushort_t smem[3*24576];   // 147,456 B; epilogue reuses as float
  int tid = threadIdx.x;
  int wave = tid >> 6, lane = tid & 63;
  // XCD swizzle: 256 blocks -> 32 contiguous per XCD
  int flat = blockIdx.x;
  int orig = (flat & 7) * 32 + (flat >> 3);
  int n0 = (orig & 3) * 128;       // 4 n-tiles (N=512)
  int m0 = (orig >> 2) * 256;      // 64 m-tiles
  int wm = (wave >> 1) * 64, wn = (wave & 1) * 64;
  int lm = lane & 15;
  int lk = lane >> 4;
  int sx = lm & 7;
  f32x4 zero4 = {0.f,0.f,0.f,0.f};
  f32x4 acc[4][4];
  #pragma unroll
  for(int i=0;i<4;i++)
    #pragma unroll
    for(int j=0;j<4;j++) acc[i][j] = zero4;

  auto STAGE = [&](int kt, int bi){
    int k0 = kt*64;
    ushort_t* As = &smem[bi*24576];
    ushort_t* Bs = &smem[bi*24576 + 16384];
    #pragma unroll
    for(int i=0;i<4;i++){
      int c = i*512 + tid, r = c >> 3, kc = c & 7;
      int kg = kc ^ (r & 7);
      gl2lds16(&A[(size_t)(m0 + r)*1024 + k0 + kg*8], &As[c*8]);
    }
    #pragma unroll
    for(int i=0;i<2;i++){
      int c = i*512 + tid, r = c >> 3, kc = c & 7;
      int kg = kc ^ (r & 7);
      gl2lds16(&Bw[(size_t)(n0 + r)*1024 + k0 + kg*8], &Bs[c*8]);
    }
  };

  STAGE(0, 0);
  STAGE(1, 1);
  for(int kt=0; kt<16; ++kt){
    int bi = kt % 3;
    if(kt + 2 < 16) STAGE(kt+2, (kt+2) % 3);
    if(kt < 14)       asm volatile("s_waitcnt vmcnt(12)" ::: "memory");
    else if(kt == 14) asm volatile("s_waitcnt vmcnt(6)"  ::: "memory");
    else              asm volatile("s_waitcnt vmcnt(0)"  ::: "memory");
    __builtin_amdgcn_sched_barrier(0);
    __builtin_amdgcn_s_barrier();
    const ushort_t* As = &smem[bi*24576];
    const ushort_t* Bs = &smem[bi*24576 + 16384];
    #pragma unroll
    for(int kk=0; kk<64; kk+=32){
      short8 af[4], bf[4];
      int ch = ((kk >> 3) + lk) ^ sx;
      #pragma unroll
      for(int i=0;i<4;i++){
        af[i] = *(const short8*)&As[(wm + i*16 + lm)*64 + ch*8];
        bf[i] = *(const short8*)&Bs[(wn + i*16 + lm)*64 + ch*8];
      }
      #pragma unroll
      for(int i=0;i<4;i++)
        #pragma unroll
        for(int j=0;j<4;j++)
          acc[i][j] = __builtin_amdgcn_mfma_f32_16x16x32_bf16(af[i], bf[j], acc[i][j], 0, 0, 0);
    }
    __builtin_amdgcn_s_barrier();
  }
  // epilogue: 4 n-groups of 32; T float [32][264]; coalesced float4 stores along l (256 wide)
  float* T = (float*)smem;               // 32*264*4 = 33,792 B
  int b = m0 >> 12, l0 = m0 & 4095;
  for(int g=0; g<4; ++g){
    __syncthreads();
    if((wave & 1) == (g >> 1)){
      int jg = g & 1;
      #pragma unroll
      for(int j2=0;j2<2;j2++){
        int j = jg*2 + j2;
        #pragma unroll
        for(int i=0;i<4;i++)
          #pragma unroll
          for(int r=0;r<4;r++){
            int ml = wm + i*16 + lk*4 + r;             // 0..255
            int nl = wn + j*16 + lm - g*32;            // 0..31
            T[nl*264 + ml] = acc[i][j][r];
          }
      }
    }
    __syncthreads();
    int nl = tid >> 4, seg = tid & 15;   // 32 rows x 16 segs x 16 floats
    float* dst = &out[((size_t)b*DIM + n0 + g*32 + nl)*LEN + l0 + seg*16];
    #pragma unroll
    for(int k=0;k<4;k++){
      float4 v = *(const float4*)&T[nl*264 + seg*16 + k*4];
      *(float4*)&dst[k*4] = v;
    }
  }
}

extern "C" void kernel_launch(void* const* d_in, const int* in_sizes, int n_in,
                              void* d_out, int out_size, void* d_ws, size_t ws_size,
                              hipStream_t stream) {
  const float* x    = (const float*)d_in[0];
  const float* lnw  = (const float*)d_in[1];
  const float* lnb  = (const float*)d_in[2];
  const float* Win  = (const float*)d_in[3];
  const float* cw   = (const float*)d_in[4];
  const float* cb   = (const float*)d_in[5];
  const float* Wxp  = (const float*)d_in[6];
  const float* Wdt  = (const float*)d_in[7];
  const float* bdt  = (const float*)d_in[8];
  const float* Alog = (const float*)d_in[9];
  const float* Dp   = (const float*)d_in[10];
  const float* Wout = (const float*)d_in[11];
  float* out = (float*)d_out;
  float* ws  = (float*)d_ws;

  // workspace layout (float-slot offsets), total 147.25 MiB — no overlapping live ranges
  float*    mu   = ws;                          // 16384
  float*    rs   = ws + 16384;                  // 16384
  _Float16* xin  = (_Float16*)(ws + 32768);     // fp16, 16,777,216 halves (live gemm1..conv)
  _Float16* dF   = (_Float16*)(ws + 32768);     // same region, disjoint lifetime (deltag..scanC)
  float*    E    = ws + 32768 + 8388608;        // 4,194,304 fl (Hs in-place)
  float*    cum  = ws + 32768 + 12582912;       // 262,144 fl
  ushort_t* sz   = (ushort_t*)(ws + 32768 + 16777216);            // bf16 16,777,216
  ushort_t* u    = (ushort_t*)(ws + 32768 + 16777216 + 8388608);  // bf16 16,777,216 (y overwrites)
  ushort_t* xnT  = (ushort_t*)(ws + 32768 + 16777216 + 16777216); // bf16 8,388,608
  float*    dbl  = (float*)xnT;                 // alias after gemm1: 1,048,576 fp32
  ushort_t* Winb = (ushort_t*)(ws + 32768 + 16777216 + 16777216 + 4194304);
  ushort_t* Woutb= Winb + 1048576;
  ushort_t* Wxpb = Woutb + 524288;

  hipLaunchKernelGGL(ln_stats_k, dim3(256),     dim3(256), 0, stream, x, mu, rs);
  hipLaunchKernelGGL(wcvt_k,     dim3(6400),    dim3(256), 0, stream, Win, Wout, Wxp, Winb, Woutb, Wxpb);
  hipLaunchKernelGGL(xnt_k,      dim3(2048),    dim3(256), 0, stream, x, mu, rs, lnw, lnb, xnT);
  hipLaunchKernelGGL(gemm1_mfma, dim3(1024),    dim3(512), 0, stream, xnT, Winb, xin, sz);
  hipLaunchKernelGGL(conv_silu_k,dim3(1024),    dim3(256), 0, stream, xin, cw, cb, u);
  hipLaunchKernelGGL(gemm2_mfma, dim3(256),     dim3(256), 0, stream, u, Wxpb, dbl);
  hipLaunchKernelGGL(deltag_k,   dim3(1024),    dim3(256), 0, stream, dbl, Wdt, bdt, dF);
  hipLaunchKernelGGL(scanA_k,    dim3(1024),    dim3(256), 0, stream, u, dbl, Alog, dF, E, cum);
  hipLaunchKernelGGL(scanB_k,    dim3(256),     dim3(256), 0, stream, cum, Alog, E);
  hipLaunchKernelGGL(scanC_k,    dim3(1024),    dim3(256), 0, stream, u, dbl, Alog, E, Dp, sz, dF);
  hipLaunchKernelGGL(gemm4_mfma, dim3(256),     dim3(512), 0, stream, u, Woutb, out);
}

// Round 7
// 358.911 us; speedup vs baseline: 1.0315x; 1.0315x over previous
//
#include <hip/hip_runtime.h>
#include <math.h>

#define Bsz 4
#define DIM 512
#define LEN 4096
#define DST 16
#define DIN 1024
#define NCH 64    // chunks over L
#define CHL 64    // chunk length

typedef unsigned short ushort_t;
typedef unsigned int uint_t;
typedef __attribute__((ext_vector_type(8))) short short8;          // 8 bf16 (4 VGPRs)
typedef __attribute__((ext_vector_type(8))) unsigned short ushort8;
typedef __attribute__((ext_vector_type(8))) _Float16 half8;        // 8 fp16
typedef __attribute__((ext_vector_type(4))) float f32x4;

__device__ __forceinline__ float sigmoidf_(float x){ return 1.0f/(1.0f+__expf(-x)); }
__device__ __forceinline__ float bf2f(ushort_t u){ return __uint_as_float(((uint_t)u) << 16); }
__device__ __forceinline__ ushort_t f2bf(float f){
  uint_t x = __float_as_uint(f);
  uint_t r = (x + 0x7FFFu + ((x >> 16) & 1u)) >> 16;
  return (ushort_t)r;
}
__device__ __forceinline__ ushort_t f2h_bits(float f){
  _Float16 h = (_Float16)f;
  union { _Float16 h; ushort_t u; } v; v.h = h; return v.u;
}
__device__ __forceinline__ void gl2lds16(const void* g, void* l){
  __builtin_amdgcn_global_load_lds((const __attribute__((address_space(1))) void*)g,
                                   (__attribute__((address_space(3))) void*)l, 16, 0, 0);
}
// a^1..a^16 from a1=exp(-dv), log-depth
#define POW_CHAIN(av, a1) \
  { float a2=a1*a1, a4=a2*a2, a8=a4*a4; \
    av[0]=a1; av[1]=a2; av[2]=a2*a1; av[3]=a4; \
    av[4]=a4*a1; av[5]=a4*a2; av[6]=a4*av[2]; av[7]=a8; \
    av[8]=a8*a1; av[9]=a8*a2; av[10]=a8*av[2]; av[11]=a8*a4; \
    av[12]=a8*av[4]; av[13]=a8*av[5]; av[14]=a8*av[6]; av[15]=a8*a8; }

__device__ __forceinline__ bool load_nA(const float* Alog, int d, float* nA){
  bool fast = true;
  #pragma unroll
  for(int s=0;s<DST;s++){
    float v = -__expf(Alog[d*DST+s]);
    float tgt = -(float)(s+1);
    if(fabsf(v - tgt) < 1e-4f*(float)(s+1)) v = tgt;
    else fast = false;
    nA[s] = v;
  }
  return fast;
}

// ---------------- fused LayerNorm stats + apply + transpose -> xnT bf16 [B*L][512] ----------------
// One block per (b, 64 l-rows): stream x once into LDS (f32, [64][513] pad -> conflict-free),
// accumulate sums in-flight, reduce -> mu/rs, then normalize from LDS and write bf16 transpose.
// HBM: 128MB read + 16MB write, once (was 2x 128MB reads across ln_stats_k + xnt_k).
__global__ __launch_bounds__(256) void lnxnt_k(const float* __restrict__ x,
    const float* __restrict__ lnw, const float* __restrict__ lnb, ushort_t* __restrict__ xnT){
  __shared__ float xs[64][513];            // 131,328 B
  __shared__ float rsum[4][64], rsq[4][64];
  __shared__ float mu_s[64], rs_s[64];
  int bid = blockIdx.x;                    // 256 = Bsz * 64
  int lt = bid & 63;
  int b = bid >> 6;
  int l0 = lt*64;
  int ll = threadIdx.x & 63;
  int dq = threadIdx.x >> 6;               // 0..3
  const float* xb = x + (size_t)b*DIM*LEN + l0 + ll;
  float s = 0.f, sq = 0.f;
  #pragma unroll 8
  for(int i=0;i<128;i++){
    int d = dq*128 + i;
    float v = xb[(size_t)d*LEN];
    xs[ll][d] = v;
    s += v; sq += v*v;
  }
  rsum[dq][ll] = s; rsq[dq][ll] = sq;
  __syncthreads();
  if(threadIdx.x < 64){
    float ts = 0.f, tq = 0.f;
    #pragma unroll
    for(int g=0; g<4; ++g){ ts += rsum[g][ll]; tq += rsq[g][ll]; }
    float m = ts * (1.0f/DIM);
    float var = tq * (1.0f/DIM) - m*m;
    mu_s[ll] = m;
    rs_s[ll] = rsqrtf(var + 1e-5f);
  }
  __syncthreads();
  // pass 2: 4 threads per row; interleaved 8-d chunks (stride 32) -> <=2-way LDS bank aliasing
  int lr = threadIdx.x >> 2, seg = threadIdx.x & 3;
  float m = mu_s[lr], r = rs_s[lr];
  ushort_t* dst = &xnT[(size_t)(b*LEN + l0 + lr)*DIM];
  #pragma unroll
  for(int k=0;k<16;k++){
    int d0 = seg*8 + k*32;
    ushort8 o;
    #pragma unroll
    for(int j=0;j<8;j++){
      int d = d0 + j;
      o[j] = f2bf((xs[lr][d] - m)*r*lnw[d] + lnb[d]);
    }
    *(ushort8*)&dst[d0] = o;
  }
}

// ---------------- weights -> bf16 ----------------
__global__ __launch_bounds__(256) void wcvt_k(const float* __restrict__ Win,
    const float* __restrict__ Wout, const float* __restrict__ Wxp,
    ushort_t* __restrict__ Winb, ushort_t* __restrict__ Woutb, ushort_t* __restrict__ Wxpb){
  int i = blockIdx.x*256 + threadIdx.x;   // 1,638,400 total
  if(i < 1048576) Winb[i] = f2bf(Win[i]);
  else if(i < 1572864) Woutb[i-1048576] = f2bf(Wout[i-1048576]);
  else if(i < 1638400) Wxpb[i-1572864] = f2bf(Wxp[i-1572864]);
}

// ---------------- GEMM1 MFMA v6 (R4 best): dbuf gl2lds + counted vmcnt ----------------
// xnT[16384][512] x Winb[2048][512] -> xin fp16 (n<1024) / sz bf16 (n>=1024)
__global__ __launch_bounds__(256) void gemm1_mfma(const ushort_t* __restrict__ A,
    const ushort_t* __restrict__ Bw, _Float16* __restrict__ xin, ushort_t* __restrict__ sz){
  __shared__ __align__(16) ushort_t smem[2*16384];   // 2 bufs x (As 8192 + Bs 8192) = 64 KiB
  int tid = threadIdx.x;
  int wave = tid >> 6, lane = tid & 63;
  // XCD-aware swizzle: 2048 blocks, 8 XCDs -> 256 contiguous tiles per XCD
  int flat = blockIdx.y * 16 + blockIdx.x;
  int orig = (flat & 7) * 256 + (flat >> 3);
  int n0 = (orig & 15) * 128;
  int m0 = (orig >> 4) * 128;
  int wm = (wave >> 1) * 64, wn = (wave & 1) * 64;
  int lm = lane & 15;
  int lk = lane >> 4;
  int sx = lm & 7;                     // read-side XOR key (row&7 == lm&7)
  f32x4 zero4 = {0.f,0.f,0.f,0.f};
  f32x4 acc[4][4];
  #pragma unroll
  for(int i=0;i<4;i++)
    #pragma unroll
    for(int j=0;j<4;j++) acc[i][j] = zero4;
  // prologue: stage t=0 into buf 0
  #pragma unroll
  for(int i=0;i<4;i++){
    int c = i*256 + tid, r = c >> 3, kc = c & 7;
    int kg = kc ^ (r & 7);
    gl2lds16(&A [(size_t)(m0 + r)*512 + kg*8], &smem[c*8]);
    gl2lds16(&Bw[(size_t)(n0 + r)*512 + kg*8], &smem[8192 + c*8]);
  }
  int cur = 0;
  for(int t=0; t<8; ++t){
    if(t < 7){
      int k0n = (t+1)*64;
      ushort_t* Ad = &smem[(cur^1)*16384];
      ushort_t* Bd = &smem[(cur^1)*16384 + 8192];
      #pragma unroll
      for(int i=0;i<4;i++){
        int c = i*256 + tid, r = c >> 3, kc = c & 7;
        int kg = kc ^ (r & 7);
        gl2lds16(&A [(size_t)(m0 + r)*512 + k0n + kg*8], &Ad[c*8]);
        gl2lds16(&Bw[(size_t)(n0 + r)*512 + k0n + kg*8], &Bd[c*8]);
      }
      asm volatile("s_waitcnt vmcnt(8)" ::: "memory");   // stage(t) landed; t+1 stays in flight
    } else {
      asm volatile("s_waitcnt vmcnt(0)" ::: "memory");   // final: drain stage(7)
    }
    __builtin_amdgcn_sched_barrier(0);
    __builtin_amdgcn_s_barrier();      // all waves: buf[cur] complete
    const ushort_t* As = &smem[cur*16384];
    const ushort_t* Bs = &smem[cur*16384 + 8192];
    #pragma unroll
    for(int kk=0; kk<64; kk+=32){
      short8 af[4], bf[4];
      int ch = ((kk >> 3) + lk) ^ sx;   // swizzled 16B-chunk index
      #pragma unroll
      for(int i=0;i<4;i++){
        af[i] = *(const short8*)&As[(wm + i*16 + lm)*64 + ch*8];
        bf[i] = *(const short8*)&Bs[(wn + i*16 + lm)*64 + ch*8];
      }
      #pragma unroll
      for(int i=0;i<4;i++)
        #pragma unroll
        for(int j=0;j<4;j++)
          acc[i][j] = __builtin_amdgcn_mfma_f32_16x16x32_bf16(af[i], bf[j], acc[i][j], 0, 0, 0);
    }
    __builtin_amdgcn_s_barrier();      // exec sync: next iter may overwrite buf[cur^1]
    cur ^= 1;
  }
  // epilogue: LDS transpose (ushort [128][136]) + coalesced 16B stores
  ushort_t* T = smem;                      // 128*136 = 17,408 ushorts <= 32,768
  bool is_z = (n0 >= 1024);
  #pragma unroll
  for(int i=0;i<4;i++)
    #pragma unroll
    for(int j=0;j<4;j++)
      #pragma unroll
      for(int r=0;r<4;r++){
        int ml = wm + i*16 + lk*4 + r;
        int nl = wn + j*16 + lm;
        float v = acc[i][j][r];
        T[ml*136 + nl] = is_z ? f2bf(v * sigmoidf_(v)) : f2h_bits(v);
      }
  __syncthreads();
  int rr = tid >> 4, cc = (tid & 15)*8;
  #pragma unroll
  for(int p=0;p<8;p++){
    int row = p*16 + rr;
    ushort8 v = *(const ushort8*)&T[row*136 + cc];
    if(!is_z) *(ushort8*)((ushort_t*)xin + (size_t)(m0+row)*DIN + n0 + cc) = v;
    else      *(ushort8*)&sz[(size_t)(m0+row)*DIN + (n0-1024) + cc] = v;
  }
}

// ---------------- conv1d + SiLU -> u bf16 (streaming: 8 d x 8 l per thread) ----------------
__global__ __launch_bounds__(256) void conv_silu_k(const _Float16* __restrict__ xin,
    const float* __restrict__ cw, const float* __restrict__ cb, ushort_t* __restrict__ u){
  int idx = blockIdx.x*256 + threadIdx.x;   // 262,144 threads: (b, lc, dg)
  int dg = idx & 127;
  int lc = (idx >> 7) & 511;                // 512 chunks of 8 l
  int b  = idx >> 16;
  int d0 = dg*8;
  int l0 = lc*8;
  float bias[8];
  #pragma unroll
  for(int k=0;k<8;k+=4){
    float4 c4 = *(const float4*)&cb[d0+k];
    bias[k]=c4.x; bias[k+1]=c4.y; bias[k+2]=c4.z; bias[k+3]=c4.w;
  }
  float w[8][4];
  #pragma unroll
  for(int k=0;k<8;k++){
    float4 c4 = *(const float4*)&cw[(d0+k)*4];
    w[k][0]=c4.x; w[k][1]=c4.y; w[k][2]=c4.z; w[k][3]=c4.w;
  }
  const _Float16* base = xin + ((size_t)b*LEN)*DIN + d0;
  ushort_t* ub = u + ((size_t)b*LEN)*DIN + d0;
  float f0[8], f1[8], f2[8];
  if(lc > 0){
    half8 h0 = *(const half8*)&base[(size_t)(l0-3)*DIN];
    half8 h1 = *(const half8*)&base[(size_t)(l0-2)*DIN];
    half8 h2 = *(const half8*)&base[(size_t)(l0-1)*DIN];
    #pragma unroll
    for(int k=0;k<8;k++){ f0[k]=(float)h0[k]; f1[k]=(float)h1[k]; f2[k]=(float)h2[k]; }
  } else {
    #pragma unroll
    for(int k=0;k<8;k++){ f0[k]=0.f; f1[k]=0.f; f2[k]=0.f; }
  }
  #pragma unroll
  for(int t=0;t<8;t++){
    half8 xv = *(const half8*)&base[(size_t)(l0+t)*DIN];
    float f3[8];
    #pragma unroll
    for(int k=0;k<8;k++) f3[k] = (float)xv[k];
    short8 o;
    #pragma unroll
    for(int k=0;k<8;k++){
      float a = bias[k] + f0[k]*w[k][0] + f1[k]*w[k][1] + f2[k]*w[k][2] + f3[k]*w[k][3];
      float v = a * sigmoidf_(a);
      o[k] = (short)f2bf(v);
    }
    *(short8*)&ub[(size_t)(l0+t)*DIN] = o;
    #pragma unroll
    for(int k=0;k<8;k++){ f0[k]=f1[k]; f1[k]=f2[k]; f2[k]=f3[k]; }
  }
}

// ---------------- GEMM2 MFMA v3: BM=64 (256 blocks, full CU coverage) + counted vmcnt ----------
// u[16384][1024] x Wxpb[64][1024] -> dbl fp32 [16384][64]
__global__ __launch_bounds__(256) void gemm2_mfma(const ushort_t* __restrict__ A,
    const ushort_t* __restrict__ Bw, float* __restrict__ dbl){
  __shared__ __align__(16) ushort_t smem[2*8192];   // 2 bufs x (As 4096 + Bs 4096) = 32 KiB
  int tid = threadIdx.x;
  int wave = tid >> 6, lane = tid & 63;
  int m0 = blockIdx.x * 64;
  int wm = (wave >> 1) * 32, wn = (wave & 1) * 32;
  int lm = lane & 15;
  int lk = lane >> 4;
  int sx = lm & 7;
  f32x4 zero4 = {0.f,0.f,0.f,0.f};
  f32x4 acc[2][2];
  #pragma unroll
  for(int i=0;i<2;i++){ acc[i][0] = zero4; acc[i][1] = zero4; }
  // prologue: stage t=0 into buf 0
  #pragma unroll
  for(int i=0;i<2;i++){
    int c = i*256 + tid, r = c >> 3, kc = c & 7;
    int kg = kc ^ (r & 7);
    gl2lds16(&A [(size_t)(m0 + r)*1024 + kg*8], &smem[c*8]);
    gl2lds16(&Bw[(size_t)r*1024 + kg*8], &smem[4096 + c*8]);
  }
  int cur = 0;
  for(int t=0; t<16; ++t){
    if(t < 15){
      int k0n = (t+1)*64;
      ushort_t* Ad = &smem[(cur^1)*8192];
      ushort_t* Bd = &smem[(cur^1)*8192 + 4096];
      #pragma unroll
      for(int i=0;i<2;i++){
        int c = i*256 + tid, r = c >> 3, kc = c & 7;
        int kg = kc ^ (r & 7);
        gl2lds16(&A [(size_t)(m0 + r)*1024 + k0n + kg*8], &Ad[c*8]);
        gl2lds16(&Bw[(size_t)r*1024 + k0n + kg*8], &Bd[c*8]);
      }
      asm volatile("s_waitcnt vmcnt(4)" ::: "memory");
    } else {
      asm volatile("s_waitcnt vmcnt(0)" ::: "memory");
    }
    __builtin_amdgcn_sched_barrier(0);
    __builtin_amdgcn_s_barrier();
    const ushort_t* As = &smem[cur*8192];
    const ushort_t* Bs = &smem[cur*8192 + 4096];
    #pragma unroll
    for(int kk=0; kk<64; kk+=32){
      short8 af[2], bf[2];
      int ch = ((kk >> 3) + lk) ^ sx;
      #pragma unroll
      for(int i=0;i<2;i++) af[i] = *(const short8*)&As[(wm + i*16 + lm)*64 + ch*8];
      #pragma unroll
      for(int j=0;j<2;j++) bf[j] = *(const short8*)&Bs[(wn + j*16 + lm)*64 + ch*8];
      #pragma unroll
      for(int i=0;i<2;i++)
        #pragma unroll
        for(int j=0;j<2;j++)
          acc[i][j] = __builtin_amdgcn_mfma_f32_16x16x32_bf16(af[i], bf[j], acc[i][j], 0, 0, 0);
    }
    __builtin_amdgcn_s_barrier();
    cur ^= 1;
  }
  #pragma unroll
  for(int i=0;i<2;i++)
    #pragma unroll
    for(int j=0;j<2;j++)
      #pragma unroll
      for(int r=0;r<4;r++){
        int m = m0 + wm + i*16 + lk*4 + r;
        int n = wn + j*16 + lm;
        dbl[(size_t)m*64 + n] = acc[i][j][r];
      }
}

// ---------------- deltag: dv[m,d] = softplus(dbl[m,0:32]·Wdt[d,:]+bdt[d]) -> fp16 ----------------
__global__ __launch_bounds__(256,4) void deltag_k(const float* __restrict__ dbl,
    const float* __restrict__ Wdt, const float* __restrict__ bdt,
    _Float16* __restrict__ dF){
  __shared__ __align__(16) float dts[64*32];
  int bid = blockIdx.x;              // 256 m-tiles x 4 d-tiles = 1024
  int d0 = (bid & 3) * 256;
  int m0 = (bid >> 2) * 64;
  int tid = threadIdx.x;
  const f32x4* src4 = (const f32x4*)(dbl + (size_t)m0*64);
  f32x4* dst4 = (f32x4*)dts;
  for(int i=tid; i<64*8; i+=256){
    int row = i >> 3, q = i & 7;
    dst4[i] = src4[row*16 + q];
  }
  int d = d0 + tid;
  float w[32];
  #pragma unroll
  for(int k=0;k<32;k+=4){
    float4 t4 = *(const float4*)&Wdt[d*32+k];
    w[k]=t4.x; w[k+1]=t4.y; w[k+2]=t4.z; w[k+3]=t4.w;
  }
  float bd = bdt[d];
  __syncthreads();
  for(int m=0;m<64;m++){
    const float* row = dts + m*32;
    float dtv = bd;
    #pragma unroll
    for(int k=0;k<32;k+=4){
      f32x4 q = *(const f32x4*)&row[k];
      dtv += q.x*w[k] + q.y*w[k+1] + q.z*w[k+2] + q.w*w[k+3];
    }
    float dv = dtv > 15.f ? dtv : __logf(1.f + __expf(dtv));
    dF[(size_t)(m0+m)*DIN + d] = (_Float16)dv;
  }
}

// ---------------- scan phase A: per-chunk local end state + cumD ----------------
__global__ __launch_bounds__(256,4) void scanA_k(const ushort_t* __restrict__ u,
    const float* __restrict__ dbl, const float* __restrict__ Alog,
    const _Float16* __restrict__ dF,
    float* __restrict__ E, float* __restrict__ cum){
  __shared__ __align__(16) float dch[CHL*16];   // B cols
  int bid = blockIdx.x;            // NCH*4*Bsz = 1024
  int c = bid & (NCH-1);
  int dblk = (bid >> 6) & 3;
  int b = bid >> 8;
  int d = dblk*256 + threadIdx.x;
  const f32x4* src = (const f32x4*)(dbl + ((size_t)b*LEN + c*CHL)*64);
  f32x4* dst4 = (f32x4*)dch;
  for(int i=threadIdx.x; i<CHL*4; i+=256){
    int t = i >> 2, q = i & 3;
    dst4[i] = src[t*16 + 8 + q];
  }
  float nA[DST];
  bool fast = load_nA(Alog, d, nA);
  float Es[DST];
  #pragma unroll
  for(int s=0;s<DST;s++) Es[s] = 0.f;
  float cumD = 0.f;
  __syncthreads();
  const ushort_t*  uu = u  + ((size_t)b*LEN + c*CHL)*DIN + d;
  const _Float16*  pd = dF + ((size_t)b*LEN + c*CHL)*DIN + d;
  if(fast){
    for(int t=0;t<CHL;++t){
      float dv = (float)pd[(size_t)t*DIN];
      float uv = bf2f(uu[(size_t)t*DIN]);
      float du = dv*uv;
      cumD += dv;
      float a1 = __expf(-dv);
      float av[DST];
      POW_CHAIN(av, a1);
      const f32x4* r4 = (const f32x4*)(dch + t*16);
      f32x4 B0=r4[0], B1=r4[1], B2=r4[2], B3=r4[3];
      Es[0]=av[0]*Es[0]+du*B0.x;  Es[1]=av[1]*Es[1]+du*B0.y;
      Es[2]=av[2]*Es[2]+du*B0.z;  Es[3]=av[3]*Es[3]+du*B0.w;
      Es[4]=av[4]*Es[4]+du*B1.x;  Es[5]=av[5]*Es[5]+du*B1.y;
      Es[6]=av[6]*Es[6]+du*B1.z;  Es[7]=av[7]*Es[7]+du*B1.w;
      Es[8]=av[8]*Es[8]+du*B2.x;  Es[9]=av[9]*Es[9]+du*B2.y;
      Es[10]=av[10]*Es[10]+du*B2.z; Es[11]=av[11]*Es[11]+du*B2.w;
      Es[12]=av[12]*Es[12]+du*B3.x; Es[13]=av[13]*Es[13]+du*B3.y;
      Es[14]=av[14]*Es[14]+du*B3.z; Es[15]=av[15]*Es[15]+du*B3.w;
    }
  } else {
    for(int t=0;t<CHL;++t){
      float dv = (float)pd[(size_t)t*DIN];
      float uv = bf2f(uu[(size_t)t*DIN]);
      float du = dv*uv;
      cumD += dv;
      const float* row = dch + t*16;
      #pragma unroll
      for(int s=0;s<DST;s++){
        float a = __expf(dv*nA[s]);
        Es[s] = a*Es[s] + du*row[s];
      }
    }
  }
  size_t o = (size_t)(b*NCH + c)*DST*DIN + d;
  #pragma unroll
  for(int s=0;s<DST;s++) E[o + (size_t)s*DIN] = Es[s];
  cum[(size_t)(b*NCH + c)*DIN + d] = cumD;
}

// ---------------- scan phase B: combine chunk boundaries; Hs in-place over E ----------------
__global__ __launch_bounds__(256) void scanB_k(const float* __restrict__ cum,
    const float* __restrict__ Alog, float* __restrict__ E){
  int g = blockIdx.x*256 + threadIdx.x;   // 65536 = Bsz*DST*DIN
  int d = g & 1023;
  int s = (g >> 10) & 15;
  int b = g >> 14;
  float v = -__expf(Alog[d*DST + s]);
  float tgt = -(float)(s+1);
  float nA = (fabsf(v - tgt) < 1e-4f*(float)(s+1)) ? tgt : v;
  float h = 0.f;
  for(int c=0;c<NCH;c++){
    float p = __expf(cum[(size_t)(b*NCH + c)*DIN + d] * nA);
    size_t o = (size_t)((b*NCH + c)*DST + s)*DIN + d;
    float e = E[o];
    E[o] = h;
    h = p*h + e;
  }
}

// ---------------- scan phase C: replay, y=(scan+u*D)*sz, y bf16 over u ----------------
__global__ __launch_bounds__(256,4) void scanC_k(ushort_t* __restrict__ u,
    const float* __restrict__ dbl, const float* __restrict__ Alog,
    const float* __restrict__ Hs, const float* __restrict__ Dp, const ushort_t* __restrict__ sz,
    const _Float16* __restrict__ dF){
  __shared__ __align__(16) float dch[CHL*32];   // B,C cols
  int bid = blockIdx.x;
  int c = bid & (NCH-1);
  int dblk = (bid >> 6) & 3;
  int b = bid >> 8;
  int d = dblk*256 + threadIdx.x;
  const f32x4* src = (const f32x4*)(dbl + ((size_t)b*LEN + c*CHL)*64);
  f32x4* dst4 = (f32x4*)dch;
  for(int i=threadIdx.x; i<CHL*8; i+=256){
    int t = i >> 3, q = i & 7;
    dst4[i] = src[t*16 + 8 + q];
  }
  float nA[DST];
  bool fast = load_nA(Alog, d, nA);
  float h[DST];
  size_t ho = (size_t)(b*NCH + c)*DST*DIN + d;
  #pragma unroll
  for(int s=0;s<DST;s++) h[s] = Hs[ho + (size_t)s*DIN];
  float Dv = Dp[d];
  __syncthreads();
  ushort_t* uu = u + ((size_t)b*LEN + c*CHL)*DIN + d;
  const ushort_t* zz = sz + ((size_t)b*LEN + c*CHL)*DIN + d;
  const _Float16* pd = dF + ((size_t)b*LEN + c*CHL)*DIN + d;
  if(fast){
    for(int t=0;t<CHL;++t){
      float dv = (float)pd[(size_t)t*DIN];
      float uv = bf2f(uu[(size_t)t*DIN]);
      float du = dv*uv;
      float a1 = __expf(-dv);
      float av[DST];
      POW_CHAIN(av, a1);
      const f32x4* r4 = (const f32x4*)(dch + t*32);
      f32x4 B0=r4[0], B1=r4[1], B2=r4[2], B3=r4[3];
      f32x4 C0=r4[4], C1=r4[5], C2=r4[6], C3=r4[7];
      float y0, y1, y2, y3;
      h[0]=av[0]*h[0]+du*B0.x;  h[1]=av[1]*h[1]+du*B0.y;
      h[2]=av[2]*h[2]+du*B0.z;  h[3]=av[3]*h[3]+du*B0.w;
      y0 = h[0]*C0.x + h[1]*C0.y; y1 = h[2]*C0.z + h[3]*C0.w;
      h[4]=av[4]*h[4]+du*B1.x;  h[5]=av[5]*h[5]+du*B1.y;
      h[6]=av[6]*h[6]+du*B1.z;  h[7]=av[7]*h[7]+du*B1.w;
      y2 = h[4]*C1.x + h[5]*C1.y; y3 = h[6]*C1.z + h[7]*C1.w;
      h[8]=av[8]*h[8]+du*B2.x;  h[9]=av[9]*h[9]+du*B2.y;
      h[10]=av[10]*h[10]+du*B2.z; h[11]=av[11]*h[11]+du*B2.w;
      y0 += h[8]*C2.x + h[9]*C2.y; y1 += h[10]*C2.z + h[11]*C2.w;
      h[12]=av[12]*h[12]+du*B3.x; h[13]=av[13]*h[13]+du*B3.y;
      h[14]=av[14]*h[14]+du*B3.z; h[15]=av[15]*h[15]+du*B3.w;
      y2 += h[12]*C3.x + h[13]*C3.y; y3 += h[14]*C3.z + h[15]*C3.w;
      float y = (y0+y1) + (y2+y3) + uv*Dv;
      y *= bf2f(zz[(size_t)t*DIN]);
      uu[(size_t)t*DIN] = f2bf(y);
    }
  } else {
    for(int t=0;t<CHL;++t){
      float dv = (float)pd[(size_t)t*DIN];
      float uv = bf2f(uu[(size_t)t*DIN]);
      float du = dv*uv;
      const float* row = dch + t*32;
      float y = 0.f;
      #pragma unroll
      for(int s=0;s<DST;s++){
        float a = __expf(dv*nA[s]);
        h[s] = a*h[s] + du*row[s];
        y += h[s]*row[16+s];
      }
      y += uv*Dv;
      y *= bf2f(zz[(size_t)t*DIN]);
      uu[(size_t)t*DIN] = f2bf(y);
    }
  }
}

// ---------------- GEMM4 MFMA v6 (R4 best): dbuf gl2lds + counted vmcnt ----------------
// y[16384][1024] x Woutb[512][1024] -> out[b][n][l]
__global__ __launch_bounds__(256) void gemm4_mfma(const ushort_t* __restrict__ A,
    const ushort_t* __restrict__ Bw, float* __restrict__ out){
  __shared__ __align__(16) ushort_t smem[2*16384];   // 64 KiB; epilogue reuses as float
  int tid = threadIdx.x;
  int wave = tid >> 6, lane = tid & 63;
  // XCD-aware swizzle: 512 blocks, 8 XCDs -> 64 contiguous tiles per XCD
  int flat = blockIdx.y * 4 + blockIdx.x;
  int orig = (flat & 7) * 64 + (flat >> 3);
  int n0 = (orig & 3) * 128;       // N=512 -> 4
  int m0 = (orig >> 2) * 128;
  int wm = (wave >> 1) * 64, wn = (wave & 1) * 64;
  int lm = lane & 15;
  int lk = lane >> 4;
  int sx = lm & 7;
  f32x4 zero4 = {0.f,0.f,0.f,0.f};
  f32x4 acc[4][4];
  #pragma unroll
  for(int i=0;i<4;i++)
    #pragma unroll
    for(int j=0;j<4;j++) acc[i][j] = zero4;
  // prologue: stage t=0 into buf 0
  #pragma unroll
  for(int i=0;i<4;i++){
    int c = i*256 + tid, r = c >> 3, kc = c & 7;
    int kg = kc ^ (r & 7);
    gl2lds16(&A [(size_t)(m0 + r)*1024 + kg*8], &smem[c*8]);
    gl2lds16(&Bw[(size_t)(n0 + r)*1024 + kg*8], &smem[8192 + c*8]);
  }
  int cur = 0;
  for(int t=0; t<16; ++t){
    if(t < 15){
      int k0n = (t+1)*64;
      ushort_t* Ad = &smem[(cur^1)*16384];
      ushort_t* Bd = &smem[(cur^1)*16384 + 8192];
      #pragma unroll
      for(int i=0;i<4;i++){
        int c = i*256 + tid, r = c >> 3, kc = c & 7;
        int kg = kc ^ (r & 7);
        gl2lds16(&A [(size_t)(m0 + r)*1024 + k0n + kg*8], &Ad[c*8]);
        gl2lds16(&Bw[(size_t)(n0 + r)*1024 + k0n + kg*8], &Bd[c*8]);
      }
      asm volatile("s_waitcnt vmcnt(8)" ::: "memory");
    } else {
      asm volatile("s_waitcnt vmcnt(0)" ::: "memory");
    }
    __builtin_amdgcn_sched_barrier(0);
    __builtin_amdgcn_s_barrier();
    const ushort_t* As = &smem[cur*16384];
    const ushort_t* Bs = &smem[cur*16384 + 8192];
    #pragma unroll
    for(int kk=0; kk<64; kk+=32){
      short8 af[4], bf[4];
      int ch = ((kk >> 3) + lk) ^ sx;
      #pragma unroll
      for(int i=0;i<4;i++){
        af[i] = *(const short8*)&As[(wm + i*16 + lm)*64 + ch*8];
        bf[i] = *(const short8*)&Bs[(wn + i*16 + lm)*64 + ch*8];
      }
      #pragma unroll
      for(int i=0;i<4;i++)
        #pragma unroll
        for(int j=0;j<4;j++)
          acc[i][j] = __builtin_amdgcn_mfma_f32_16x16x32_bf16(af[i], bf[j], acc[i][j], 0, 0, 0);
    }
    __builtin_amdgcn_s_barrier();
    cur ^= 1;
  }
  // epilogue: LDS transpose, 32-n groups, coalesced float4 stores along l(=m)
  float* T = (float*)smem;               // [32][132] fp32 = 16,896 B
  int b = m0 >> 12, l0 = m0 & 4095;
  for(int g=0; g<4; ++g){
    __syncthreads();
    if((g >> 1) == (wave & 1)){
      int jg = g & 1;
      #pragma unroll
      for(int j2=0;j2<2;j2++){
        int j = jg*2 + j2;
        #pragma unroll
        for(int i=0;i<4;i++)
          #pragma unroll
          for(int r=0;r<4;r++){
            int ml = wm + i*16 + lk*4 + r;
            int nl = wn + j*16 + lm - g*32;
            T[nl*132 + ml] = acc[i][j][r];
          }
      }
    }
    __syncthreads();
    int nl = tid >> 3, seg = tid & 7;
    float* dst = &out[((size_t)b*DIM + n0 + g*32 + nl)*LEN + l0 + seg*16];
    #pragma unroll
    for(int k=0;k<4;k++){
      float4 v = *(const float4*)&T[nl*132 + seg*16 + k*4];
      *(float4*)&dst[k*4] = v;
    }
  }
}

extern "C" void kernel_launch(void* const* d_in, const int* in_sizes, int n_in,
                              void* d_out, int out_size, void* d_ws, size_t ws_size,
                              hipStream_t stream) {
  const float* x    = (const float*)d_in[0];
  const float* lnw  = (const float*)d_in[1];
  const float* lnb  = (const float*)d_in[2];
  const float* Win  = (const float*)d_in[3];
  const float* cw   = (const float*)d_in[4];
  const float* cb   = (const float*)d_in[5];
  const float* Wxp  = (const float*)d_in[6];
  const float* Wdt  = (const float*)d_in[7];
  const float* bdt  = (const float*)d_in[8];
  const float* Alog = (const float*)d_in[9];
  const float* Dp   = (const float*)d_in[10];
  const float* Wout = (const float*)d_in[11];
  float* out = (float*)d_out;
  float* ws  = (float*)d_ws;

  // workspace layout (float-slot offsets), total 147.25 MiB — no overlapping live ranges
  _Float16* xin  = (_Float16*)(ws + 32768);     // fp16, 16,777,216 halves (live gemm1..conv)
  _Float16* dF   = (_Float16*)(ws + 32768);     // same region, disjoint lifetime (deltag..scanC)
  float*    E    = ws + 32768 + 8388608;        // 4,194,304 fl (Hs in-place)
  float*    cum  = ws + 32768 + 12582912;       // 262,144 fl
  ushort_t* sz   = (ushort_t*)(ws + 32768 + 16777216);            // bf16 16,777,216
  ushort_t* u    = (ushort_t*)(ws + 32768 + 16777216 + 8388608);  // bf16 16,777,216 (y overwrites)
  ushort_t* xnT  = (ushort_t*)(ws + 32768 + 16777216 + 16777216); // bf16 8,388,608
  float*    dbl  = (float*)xnT;                 // alias after gemm1: 1,048,576 fp32
  ushort_t* Winb = (ushort_t*)(ws + 32768 + 16777216 + 16777216 + 4194304);
  ushort_t* Woutb= Winb + 1048576;
  ushort_t* Wxpb = Woutb + 524288;

  hipLaunchKernelGGL(wcvt_k,     dim3(6400),    dim3(256), 0, stream, Win, Wout, Wxp, Winb, Woutb, Wxpb);
  hipLaunchKernelGGL(lnxnt_k,    dim3(256),     dim3(256), 0, stream, x, lnw, lnb, xnT);
  hipLaunchKernelGGL(gemm1_mfma, dim3(16,128),  dim3(256), 0, stream, xnT, Winb, xin, sz);
  hipLaunchKernelGGL(conv_silu_k,dim3(1024),    dim3(256), 0, stream, xin, cw, cb, u);
  hipLaunchKernelGGL(gemm2_mfma, dim3(256),     dim3(256), 0, stream, u, Wxpb, dbl);
  hipLaunchKernelGGL(deltag_k,   dim3(1024),    dim3(256), 0, stream, dbl, Wdt, bdt, dF);
  hipLaunchKernelGGL(scanA_k,    dim3(1024),    dim3(256), 0, stream, u, dbl, Alog, dF, E, cum);
  hipLaunchKernelGGL(scanB_k,    dim3(256),     dim3(256), 0, stream, cum, Alog, E);
  hipLaunchKernelGGL(scanC_k,    dim3(1024),    dim3(256), 0, stream, u, dbl, Alog, E, Dp, sz, dF);
  hipLaunchKernelGGL(gemm4_mfma, dim3(4,128),   dim3(256), 0, stream, u, Woutb, out);
}

// Round 8
// 348.913 us; speedup vs baseline: 1.0611x; 1.0287x over previous
//
#include <hip/hip_runtime.h>
#include <math.h>

#define Bsz 4
#define DIM 512
#define LEN 4096
#define DST 16
#define DIN 1024
#define NCH 64    // chunks over L
#define CHL 64    // chunk length

typedef unsigned short ushort_t;
typedef unsigned int uint_t;
typedef __attribute__((ext_vector_type(8))) short short8;          // 8 bf16 (4 VGPRs)
typedef __attribute__((ext_vector_type(8))) unsigned short ushort8;
typedef __attribute__((ext_vector_type(8))) _Float16 half8;        // 8 fp16
typedef __attribute__((ext_vector_type(4))) float f32x4;

__device__ __forceinline__ float sigmoidf_(float x){ return 1.0f/(1.0f+__expf(-x)); }
__device__ __forceinline__ float bf2f(ushort_t u){ return __uint_as_float(((uint_t)u) << 16); }
__device__ __forceinline__ ushort_t f2bf(float f){
  uint_t x = __float_as_uint(f);
  uint_t r = (x + 0x7FFFu + ((x >> 16) & 1u)) >> 16;
  return (ushort_t)r;
}
__device__ __forceinline__ ushort_t f2h_bits(float f){
  _Float16 h = (_Float16)f;
  union { _Float16 h; ushort_t u; } v; v.h = h; return v.u;
}
__device__ __forceinline__ void gl2lds16(const void* g, void* l){
  __builtin_amdgcn_global_load_lds((const __attribute__((address_space(1))) void*)g,
                                   (__attribute__((address_space(3))) void*)l, 16, 0, 0);
}
// a^1..a^16 from a1=exp(-dv), log-depth
#define POW_CHAIN(av, a1) \
  { float a2=a1*a1, a4=a2*a2, a8=a4*a4; \
    av[0]=a1; av[1]=a2; av[2]=a2*a1; av[3]=a4; \
    av[4]=a4*a1; av[5]=a4*a2; av[6]=a4*av[2]; av[7]=a8; \
    av[8]=a8*a1; av[9]=a8*a2; av[10]=a8*av[2]; av[11]=a8*a4; \
    av[12]=a8*av[4]; av[13]=a8*av[5]; av[14]=a8*av[6]; av[15]=a8*a8; }

__device__ __forceinline__ bool load_nA(const float* Alog, int d, float* nA){
  bool fast = true;
  #pragma unroll
  for(int s=0;s<DST;s++){
    float v = -__expf(Alog[d*DST+s]);
    float tgt = -(float)(s+1);
    if(fabsf(v - tgt) < 1e-4f*(float)(s+1)) v = tgt;
    else fast = false;
    nA[s] = v;
  }
  return fast;
}

// ---------------- prep: weights->bf16 (blocks 0..1599) + LN stats @16 waves (blocks 1600..1855) ----
// wcvt part: 1600 blocks x 1024 threads = 1,638,400 elements exactly.
// stats part: 256 logical blocks, each 64 l-rows x 512 d with 1024 threads (16 waves/CU vs old 4):
// lanes = consecutive l (256B coalesced), dgrp = wave index; 32 d per thread -> deep load ILP.
__global__ __launch_bounds__(1024) void prep_k(const float* __restrict__ Win,
    const float* __restrict__ Wout, const float* __restrict__ Wxp,
    ushort_t* __restrict__ Winb, ushort_t* __restrict__ Woutb, ushort_t* __restrict__ Wxpb,
    const float* __restrict__ x, float* __restrict__ mu, float* __restrict__ rs){
  __shared__ float rsum[16][64], rsq[16][64];
  int bid = blockIdx.x;
  int tid = threadIdx.x;
  if(bid < 1600){
    int i = bid*1024 + tid;
    if(i < 1048576) Winb[i] = f2bf(Win[i]);
    else if(i < 1572864) Woutb[i-1048576] = f2bf(Wout[i-1048576]);
    else Wxpb[i-1572864] = f2bf(Wxp[i-1572864]);
    return;
  }
  int sid = bid - 1600;        // 0..255
  int b = sid >> 6;
  int lg = sid & 63;
  int lane = tid & 63;
  int dgrp = tid >> 6;         // 0..15
  int l = lg*64 + lane;
  const float* xb = x + (size_t)b*DIM*LEN + l;
  float s = 0.f, sq = 0.f;
  #pragma unroll 8
  for(int i=0;i<32;i++){
    int d = dgrp*32 + i;
    float v = xb[(size_t)d*LEN];
    s += v; sq += v*v;
  }
  rsum[dgrp][lane] = s; rsq[dgrp][lane] = sq;
  __syncthreads();
  if(tid < 64){
    float ts = 0.f, tq = 0.f;
    #pragma unroll
    for(int g=0; g<16; ++g){ ts += rsum[g][tid]; tq += rsq[g][tid]; }
    float m = ts * (1.0f/DIM);
    float var = tq * (1.0f/DIM) - m*m;
    mu[b*LEN + lg*64 + tid] = m;
    rs[b*LEN + lg*64 + tid] = rsqrtf(var + 1e-5f);
  }
}

// ---------------- LN apply + transpose -> xnT bf16 [B*L][512] ----------------
__global__ __launch_bounds__(256) void xnt_k(const float* __restrict__ x,
    const float* __restrict__ mu, const float* __restrict__ rs,
    const float* __restrict__ lnw, const float* __restrict__ lnb, ushort_t* __restrict__ xnT){
  __shared__ ushort_t t[64][72];
  int bid = blockIdx.x;              // 4 * 8 * 64 = 2048
  int lt = bid & 63;
  int dt_ = (bid >> 6) & 7;
  int b = bid >> 9;
  int l0 = lt*64, d0 = dt_*64;
  int ll = threadIdx.x & 63;
  int dq = threadIdx.x >> 6;
  float mul_ = mu[b*LEN + l0 + ll], rsl = rs[b*LEN + l0 + ll];
  const float* xb = x + (size_t)b*DIM*LEN;
  #pragma unroll
  for(int i=0;i<16;i++){
    int d = d0 + dq*16 + i;
    float v = xb[(size_t)d*LEN + l0 + ll];
    t[ll][dq*16 + i] = f2bf((v - mul_)*rsl*lnw[d] + lnb[d]);
  }
  __syncthreads();
  int lr = threadIdx.x >> 2, seg = threadIdx.x & 3;
  ushort_t* dst = &xnT[(size_t)(b*LEN + l0 + lr)*DIM + d0 + seg*16];
  #pragma unroll
  for(int k=0;k<4;k++){
    ushort4 v = *(const ushort4*)&t[lr][seg*16 + k*4];
    *(ushort4*)&dst[k*4] = v;
  }
}

// ---------------- GEMM1 MFMA v6 (R4 best): dbuf gl2lds + counted vmcnt ----------------
// xnT[16384][512] x Winb[2048][512] -> xin fp16 (n<1024) / sz bf16 (n>=1024)
__global__ __launch_bounds__(256) void gemm1_mfma(const ushort_t* __restrict__ A,
    const ushort_t* __restrict__ Bw, _Float16* __restrict__ xin, ushort_t* __restrict__ sz){
  __shared__ __align__(16) ushort_t smem[2*16384];   // 2 bufs x (As 8192 + Bs 8192) = 64 KiB
  int tid = threadIdx.x;
  int wave = tid >> 6, lane = tid & 63;
  // XCD-aware swizzle: 2048 blocks, 8 XCDs -> 256 contiguous tiles per XCD
  int flat = blockIdx.y * 16 + blockIdx.x;
  int orig = (flat & 7) * 256 + (flat >> 3);
  int n0 = (orig & 15) * 128;
  int m0 = (orig >> 4) * 128;
  int wm = (wave >> 1) * 64, wn = (wave & 1) * 64;
  int lm = lane & 15;
  int lk = lane >> 4;
  int sx = lm & 7;                     // read-side XOR key (row&7 == lm&7)
  f32x4 zero4 = {0.f,0.f,0.f,0.f};
  f32x4 acc[4][4];
  #pragma unroll
  for(int i=0;i<4;i++)
    #pragma unroll
    for(int j=0;j<4;j++) acc[i][j] = zero4;
  // prologue: stage t=0 into buf 0
  #pragma unroll
  for(int i=0;i<4;i++){
    int c = i*256 + tid, r = c >> 3, kc = c & 7;
    int kg = kc ^ (r & 7);
    gl2lds16(&A [(size_t)(m0 + r)*512 + kg*8], &smem[c*8]);
    gl2lds16(&Bw[(size_t)(n0 + r)*512 + kg*8], &smem[8192 + c*8]);
  }
  int cur = 0;
  for(int t=0; t<8; ++t){
    if(t < 7){
      int k0n = (t+1)*64;
      ushort_t* Ad = &smem[(cur^1)*16384];
      ushort_t* Bd = &smem[(cur^1)*16384 + 8192];
      #pragma unroll
      for(int i=0;i<4;i++){
        int c = i*256 + tid, r = c >> 3, kc = c & 7;
        int kg = kc ^ (r & 7);
        gl2lds16(&A [(size_t)(m0 + r)*512 + k0n + kg*8], &Ad[c*8]);
        gl2lds16(&Bw[(size_t)(n0 + r)*512 + k0n + kg*8], &Bd[c*8]);
      }
      asm volatile("s_waitcnt vmcnt(8)" ::: "memory");   // stage(t) landed; t+1 stays in flight
    } else {
      asm volatile("s_waitcnt vmcnt(0)" ::: "memory");   // final: drain stage(7)
    }
    __builtin_amdgcn_sched_barrier(0);
    __builtin_amdgcn_s_barrier();      // all waves: buf[cur] complete
    const ushort_t* As = &smem[cur*16384];
    const ushort_t* Bs = &smem[cur*16384 + 8192];
    #pragma unroll
    for(int kk=0; kk<64; kk+=32){
      short8 af[4], bf[4];
      int ch = ((kk >> 3) + lk) ^ sx;   // swizzled 16B-chunk index
      #pragma unroll
      for(int i=0;i<4;i++){
        af[i] = *(const short8*)&As[(wm + i*16 + lm)*64 + ch*8];
        bf[i] = *(const short8*)&Bs[(wn + i*16 + lm)*64 + ch*8];
      }
      #pragma unroll
      for(int i=0;i<4;i++)
        #pragma unroll
        for(int j=0;j<4;j++)
          acc[i][j] = __builtin_amdgcn_mfma_f32_16x16x32_bf16(af[i], bf[j], acc[i][j], 0, 0, 0);
    }
    __builtin_amdgcn_s_barrier();      // exec sync: next iter may overwrite buf[cur^1]
    cur ^= 1;
  }
  // epilogue: LDS transpose (ushort [128][136]) + coalesced 16B stores
  ushort_t* T = smem;                      // 128*136 = 17,408 ushorts <= 32,768
  bool is_z = (n0 >= 1024);
  #pragma unroll
  for(int i=0;i<4;i++)
    #pragma unroll
    for(int j=0;j<4;j++)
      #pragma unroll
      for(int r=0;r<4;r++){
        int ml = wm + i*16 + lk*4 + r;
        int nl = wn + j*16 + lm;
        float v = acc[i][j][r];
        T[ml*136 + nl] = is_z ? f2bf(v * sigmoidf_(v)) : f2h_bits(v);
      }
  __syncthreads();
  int rr = tid >> 4, cc = (tid & 15)*8;
  #pragma unroll
  for(int p=0;p<8;p++){
    int row = p*16 + rr;
    ushort8 v = *(const ushort8*)&T[row*136 + cc];
    if(!is_z) *(ushort8*)((ushort_t*)xin + (size_t)(m0+row)*DIN + n0 + cc) = v;
    else      *(ushort8*)&sz[(size_t)(m0+row)*DIN + (n0-1024) + cc] = v;
  }
}

// ---------------- conv1d + SiLU -> u bf16 (streaming: 8 d x 8 l per thread) ----------------
__global__ __launch_bounds__(256) void conv_silu_k(const _Float16* __restrict__ xin,
    const float* __restrict__ cw, const float* __restrict__ cb, ushort_t* __restrict__ u){
  int idx = blockIdx.x*256 + threadIdx.x;   // 262,144 threads: (b, lc, dg)
  int dg = idx & 127;
  int lc = (idx >> 7) & 511;                // 512 chunks of 8 l
  int b  = idx >> 16;
  int d0 = dg*8;
  int l0 = lc*8;
  float bias[8];
  #pragma unroll
  for(int k=0;k<8;k+=4){
    float4 c4 = *(const float4*)&cb[d0+k];
    bias[k]=c4.x; bias[k+1]=c4.y; bias[k+2]=c4.z; bias[k+3]=c4.w;
  }
  float w[8][4];
  #pragma unroll
  for(int k=0;k<8;k++){
    float4 c4 = *(const float4*)&cw[(d0+k)*4];
    w[k][0]=c4.x; w[k][1]=c4.y; w[k][2]=c4.z; w[k][3]=c4.w;
  }
  const _Float16* base = xin + ((size_t)b*LEN)*DIN + d0;
  ushort_t* ub = u + ((size_t)b*LEN)*DIN + d0;
  float f0[8], f1[8], f2[8];
  if(lc > 0){
    half8 h0 = *(const half8*)&base[(size_t)(l0-3)*DIN];
    half8 h1 = *(const half8*)&base[(size_t)(l0-2)*DIN];
    half8 h2 = *(const half8*)&base[(size_t)(l0-1)*DIN];
    #pragma unroll
    for(int k=0;k<8;k++){ f0[k]=(float)h0[k]; f1[k]=(float)h1[k]; f2[k]=(float)h2[k]; }
  } else {
    #pragma unroll
    for(int k=0;k<8;k++){ f0[k]=0.f; f1[k]=0.f; f2[k]=0.f; }
  }
  #pragma unroll
  for(int t=0;t<8;t++){
    half8 xv = *(const half8*)&base[(size_t)(l0+t)*DIN];
    float f3[8];
    #pragma unroll
    for(int k=0;k<8;k++) f3[k] = (float)xv[k];
    short8 o;
    #pragma unroll
    for(int k=0;k<8;k++){
      float a = bias[k] + f0[k]*w[k][0] + f1[k]*w[k][1] + f2[k]*w[k][2] + f3[k]*w[k][3];
      float v = a * sigmoidf_(a);
      o[k] = (short)f2bf(v);
    }
    *(short8*)&ub[(size_t)(l0+t)*DIN] = o;
    #pragma unroll
    for(int k=0;k<8;k++){ f0[k]=f1[k]; f1[k]=f2[k]; f2[k]=f3[k]; }
  }
}

// ---------------- GEMM2 MFMA v3: BM=64 (256 blocks, full CU coverage) + counted vmcnt ----------
// u[16384][1024] x Wxpb[64][1024] -> dbl fp32 [16384][64]
__global__ __launch_bounds__(256) void gemm2_mfma(const ushort_t* __restrict__ A,
    const ushort_t* __restrict__ Bw, float* __restrict__ dbl){
  __shared__ __align__(16) ushort_t smem[2*8192];   // 2 bufs x (As 4096 + Bs 4096) = 32 KiB
  int tid = threadIdx.x;
  int wave = tid >> 6, lane = tid & 63;
  int m0 = blockIdx.x * 64;
  int wm = (wave >> 1) * 32, wn = (wave & 1) * 32;
  int lm = lane & 15;
  int lk = lane >> 4;
  int sx = lm & 7;
  f32x4 zero4 = {0.f,0.f,0.f,0.f};
  f32x4 acc[2][2];
  #pragma unroll
  for(int i=0;i<2;i++){ acc[i][0] = zero4; acc[i][1] = zero4; }
  // prologue: stage t=0 into buf 0
  #pragma unroll
  for(int i=0;i<2;i++){
    int c = i*256 + tid, r = c >> 3, kc = c & 7;
    int kg = kc ^ (r & 7);
    gl2lds16(&A [(size_t)(m0 + r)*1024 + kg*8], &smem[c*8]);
    gl2lds16(&Bw[(size_t)r*1024 + kg*8], &smem[4096 + c*8]);
  }
  int cur = 0;
  for(int t=0; t<16; ++t){
    if(t < 15){
      int k0n = (t+1)*64;
      ushort_t* Ad = &smem[(cur^1)*8192];
      ushort_t* Bd = &smem[(cur^1)*8192 + 4096];
      #pragma unroll
      for(int i=0;i<2;i++){
        int c = i*256 + tid, r = c >> 3, kc = c & 7;
        int kg = kc ^ (r & 7);
        gl2lds16(&A [(size_t)(m0 + r)*1024 + k0n + kg*8], &Ad[c*8]);
        gl2lds16(&Bw[(size_t)r*1024 + k0n + kg*8], &Bd[c*8]);
      }
      asm volatile("s_waitcnt vmcnt(4)" ::: "memory");
    } else {
      asm volatile("s_waitcnt vmcnt(0)" ::: "memory");
    }
    __builtin_amdgcn_sched_barrier(0);
    __builtin_amdgcn_s_barrier();
    const ushort_t* As = &smem[cur*8192];
    const ushort_t* Bs = &smem[cur*8192 + 4096];
    #pragma unroll
    for(int kk=0; kk<64; kk+=32){
      short8 af[2], bf[2];
      int ch = ((kk >> 3) + lk) ^ sx;
      #pragma unroll
      for(int i=0;i<2;i++) af[i] = *(const short8*)&As[(wm + i*16 + lm)*64 + ch*8];
      #pragma unroll
      for(int j=0;j<2;j++) bf[j] = *(const short8*)&Bs[(wn + j*16 + lm)*64 + ch*8];
      #pragma unroll
      for(int i=0;i<2;i++)
        #pragma unroll
        for(int j=0;j<2;j++)
          acc[i][j] = __builtin_amdgcn_mfma_f32_16x16x32_bf16(af[i], bf[j], acc[i][j], 0, 0, 0);
    }
    __builtin_amdgcn_s_barrier();
    cur ^= 1;
  }
  #pragma unroll
  for(int i=0;i<2;i++)
    #pragma unroll
    for(int j=0;j<2;j++)
      #pragma unroll
      for(int r=0;r<4;r++){
        int m = m0 + wm + i*16 + lk*4 + r;
        int n = wn + j*16 + lm;
        dbl[(size_t)m*64 + n] = acc[i][j][r];
      }
}

// ---------------- deltag: dv[m,d] = softplus(dbl[m,0:32]·Wdt[d,:]+bdt[d]) -> fp16 ----------------
__global__ __launch_bounds__(256,4) void deltag_k(const float* __restrict__ dbl,
    const float* __restrict__ Wdt, const float* __restrict__ bdt,
    _Float16* __restrict__ dF){
  __shared__ __align__(16) float dts[64*32];
  int bid = blockIdx.x;              // 256 m-tiles x 4 d-tiles = 1024
  int d0 = (bid & 3) * 256;
  int m0 = (bid >> 2) * 64;
  int tid = threadIdx.x;
  const f32x4* src4 = (const f32x4*)(dbl + (size_t)m0*64);
  f32x4* dst4 = (f32x4*)dts;
  for(int i=tid; i<64*8; i+=256){
    int row = i >> 3, q = i & 7;
    dst4[i] = src4[row*16 + q];
  }
  int d = d0 + tid;
  float w[32];
  #pragma unroll
  for(int k=0;k<32;k+=4){
    float4 t4 = *(const float4*)&Wdt[d*32+k];
    w[k]=t4.x; w[k+1]=t4.y; w[k+2]=t4.z; w[k+3]=t4.w;
  }
  float bd = bdt[d];
  __syncthreads();
  for(int m=0;m<64;m++){
    const float* row = dts + m*32;
    float dtv = bd;
    #pragma unroll
    for(int k=0;k<32;k+=4){
      f32x4 q = *(const f32x4*)&row[k];
      dtv += q.x*w[k] + q.y*w[k+1] + q.z*w[k+2] + q.w*w[k+3];
    }
    float dv = dtv > 15.f ? dtv : __logf(1.f + __expf(dtv));
    dF[(size_t)(m0+m)*DIN + d] = (_Float16)dv;
  }
}

// ---------------- scan phase A: per-chunk local end state + cumD ----------------
__global__ __launch_bounds__(256,4) void scanA_k(const ushort_t* __restrict__ u,
    const float* __restrict__ dbl, const float* __restrict__ Alog,
    const _Float16* __restrict__ dF,
    float* __restrict__ E, float* __restrict__ cum){
  __shared__ __align__(16) float dch[CHL*16];   // B cols
  int bid = blockIdx.x;            // NCH*4*Bsz = 1024
  int c = bid & (NCH-1);
  int dblk = (bid >> 6) & 3;
  int b = bid >> 8;
  int d = dblk*256 + threadIdx.x;
  const f32x4* src = (const f32x4*)(dbl + ((size_t)b*LEN + c*CHL)*64);
  f32x4* dst4 = (f32x4*)dch;
  for(int i=threadIdx.x; i<CHL*4; i+=256){
    int t = i >> 2, q = i & 3;
    dst4[i] = src[t*16 + 8 + q];
  }
  float nA[DST];
  bool fast = load_nA(Alog, d, nA);
  float Es[DST];
  #pragma unroll
  for(int s=0;s<DST;s++) Es[s] = 0.f;
  float cumD = 0.f;
  __syncthreads();
  const ushort_t*  uu = u  + ((size_t)b*LEN + c*CHL)*DIN + d;
  const _Float16*  pd = dF + ((size_t)b*LEN + c*CHL)*DIN + d;
  if(fast){
    for(int t=0;t<CHL;++t){
      float dv = (float)pd[(size_t)t*DIN];
      float uv = bf2f(uu[(size_t)t*DIN]);
      float du = dv*uv;
      cumD += dv;
      float a1 = __expf(-dv);
      float av[DST];
      POW_CHAIN(av, a1);
      const f32x4* r4 = (const f32x4*)(dch + t*16);
      f32x4 B0=r4[0], B1=r4[1], B2=r4[2], B3=r4[3];
      Es[0]=av[0]*Es[0]+du*B0.x;  Es[1]=av[1]*Es[1]+du*B0.y;
      Es[2]=av[2]*Es[2]+du*B0.z;  Es[3]=av[3]*Es[3]+du*B0.w;
      Es[4]=av[4]*Es[4]+du*B1.x;  Es[5]=av[5]*Es[5]+du*B1.y;
      Es[6]=av[6]*Es[6]+du*B1.z;  Es[7]=av[7]*Es[7]+du*B1.w;
      Es[8]=av[8]*Es[8]+du*B2.x;  Es[9]=av[9]*Es[9]+du*B2.y;
      Es[10]=av[10]*Es[10]+du*B2.z; Es[11]=av[11]*Es[11]+du*B2.w;
      Es[12]=av[12]*Es[12]+du*B3.x; Es[13]=av[13]*Es[13]+du*B3.y;
      Es[14]=av[14]*Es[14]+du*B3.z; Es[15]=av[15]*Es[15]+du*B3.w;
    }
  } else {
    for(int t=0;t<CHL;++t){
      float dv = (float)pd[(size_t)t*DIN];
      float uv = bf2f(uu[(size_t)t*DIN]);
      float du = dv*uv;
      cumD += dv;
      const float* row = dch + t*16;
      #pragma unroll
      for(int s=0;s<DST;s++){
        float a = __expf(dv*nA[s]);
        Es[s] = a*Es[s] + du*row[s];
      }
    }
  }
  size_t o = (size_t)(b*NCH + c)*DST*DIN + d;
  #pragma unroll
  for(int s=0;s<DST;s++) E[o + (size_t)s*DIN] = Es[s];
  cum[(size_t)(b*NCH + c)*DIN + d] = cumD;
}

// ---------------- scan phase B: combine chunk boundaries; Hs in-place over E ----------------
__global__ __launch_bounds__(256) void scanB_k(const float* __restrict__ cum,
    const float* __restrict__ Alog, float* __restrict__ E){
  int g = blockIdx.x*256 + threadIdx.x;   // 65536 = Bsz*DST*DIN
  int d = g & 1023;
  int s = (g >> 10) & 15;
  int b = g >> 14;
  float v = -__expf(Alog[d*DST + s]);
  float tgt = -(float)(s+1);
  float nA = (fabsf(v - tgt) < 1e-4f*(float)(s+1)) ? tgt : v;
  float h = 0.f;
  for(int c=0;c<NCH;c++){
    float p = __expf(cum[(size_t)(b*NCH + c)*DIN + d] * nA);
    size_t o = (size_t)((b*NCH + c)*DST + s)*DIN + d;
    float e = E[o];
    E[o] = h;
    h = p*h + e;
  }
}

// ---------------- scan phase C: replay, y=(scan+u*D)*sz, y bf16 over u ----------------
__global__ __launch_bounds__(256,4) void scanC_k(ushort_t* __restrict__ u,
    const float* __restrict__ dbl, const float* __restrict__ Alog,
    const float* __restrict__ Hs, const float* __restrict__ Dp, const ushort_t* __restrict__ sz,
    const _Float16* __restrict__ dF){
  __shared__ __align__(16) float dch[CHL*32];   // B,C cols
  int bid = blockIdx.x;
  int c = bid & (NCH-1);
  int dblk = (bid >> 6) & 3;
  int b = bid >> 8;
  int d = dblk*256 + threadIdx.x;
  const f32x4* src = (const f32x4*)(dbl + ((size_t)b*LEN + c*CHL)*64);
  f32x4* dst4 = (f32x4*)dch;
  for(int i=threadIdx.x; i<CHL*8; i+=256){
    int t = i >> 3, q = i & 7;
    dst4[i] = src[t*16 + 8 + q];
  }
  float nA[DST];
  bool fast = load_nA(Alog, d, nA);
  float h[DST];
  size_t ho = (size_t)(b*NCH + c)*DST*DIN + d;
  #pragma unroll
  for(int s=0;s<DST;s++) h[s] = Hs[ho + (size_t)s*DIN];
  float Dv = Dp[d];
  __syncthreads();
  ushort_t* uu = u + ((size_t)b*LEN + c*CHL)*DIN + d;
  const ushort_t* zz = sz + ((size_t)b*LEN + c*CHL)*DIN + d;
  const _Float16* pd = dF + ((size_t)b*LEN + c*CHL)*DIN + d;
  if(fast){
    for(int t=0;t<CHL;++t){
      float dv = (float)pd[(size_t)t*DIN];
      float uv = bf2f(uu[(size_t)t*DIN]);
      float du = dv*uv;
      float a1 = __expf(-dv);
      float av[DST];
      POW_CHAIN(av, a1);
      const f32x4* r4 = (const f32x4*)(dch + t*32);
      f32x4 B0=r4[0], B1=r4[1], B2=r4[2], B3=r4[3];
      f32x4 C0=r4[4], C1=r4[5], C2=r4[6], C3=r4[7];
      float y0, y1, y2, y3;
      h[0]=av[0]*h[0]+du*B0.x;  h[1]=av[1]*h[1]+du*B0.y;
      h[2]=av[2]*h[2]+du*B0.z;  h[3]=av[3]*h[3]+du*B0.w;
      y0 = h[0]*C0.x + h[1]*C0.y; y1 = h[2]*C0.z + h[3]*C0.w;
      h[4]=av[4]*h[4]+du*B1.x;  h[5]=av[5]*h[5]+du*B1.y;
      h[6]=av[6]*h[6]+du*B1.z;  h[7]=av[7]*h[7]+du*B1.w;
      y2 = h[4]*C1.x + h[5]*C1.y; y3 = h[6]*C1.z + h[7]*C1.w;
      h[8]=av[8]*h[8]+du*B2.x;  h[9]=av[9]*h[9]+du*B2.y;
      h[10]=av[10]*h[10]+du*B2.z; h[11]=av[11]*h[11]+du*B2.w;
      y0 += h[8]*C2.x + h[9]*C2.y; y1 += h[10]*C2.z + h[11]*C2.w;
      h[12]=av[12]*h[12]+du*B3.x; h[13]=av[13]*h[13]+du*B3.y;
      h[14]=av[14]*h[14]+du*B3.z; h[15]=av[15]*h[15]+du*B3.w;
      y2 += h[12]*C3.x + h[13]*C3.y; y3 += h[14]*C3.z + h[15]*C3.w;
      float y = (y0+y1) + (y2+y3) + uv*Dv;
      y *= bf2f(zz[(size_t)t*DIN]);
      uu[(size_t)t*DIN] = f2bf(y);
    }
  } else {
    for(int t=0;t<CHL;++t){
      float dv = (float)pd[(size_t)t*DIN];
      float uv = bf2f(uu[(size_t)t*DIN]);
      float du = dv*uv;
      const float* row = dch + t*32;
      float y = 0.f;
      #pragma unroll
      for(int s=0;s<DST;s++){
        float a = __expf(dv*nA[s]);
        h[s] = a*h[s] + du*row[s];
        y += h[s]*row[16+s];
      }
      y += uv*Dv;
      y *= bf2f(zz[(size_t)t*DIN]);
      uu[(size_t)t*DIN] = f2bf(y);
    }
  }
}

// ---------------- GEMM4 MFMA v6 (R4 best): dbuf gl2lds + counted vmcnt ----------------
// y[16384][1024] x Woutb[512][1024] -> out[b][n][l]
__global__ __launch_bounds__(256) void gemm4_mfma(const ushort_t* __restrict__ A,
    const ushort_t* __restrict__ Bw, float* __restrict__ out){
  __shared__ __align__(16) ushort_t smem[2*16384];   // 64 KiB; epilogue reuses as float
  int tid = threadIdx.x;
  int wave = tid >> 6, lane = tid & 63;
  // XCD-aware swizzle: 512 blocks, 8 XCDs -> 64 contiguous tiles per XCD
  int flat = blockIdx.y * 4 + blockIdx.x;
  int orig = (flat & 7) * 64 + (flat >> 3);
  int n0 = (orig & 3) * 128;       // N=512 -> 4
  int m0 = (orig >> 2) * 128;
  int wm = (wave >> 1) * 64, wn = (wave & 1) * 64;
  int lm = lane & 15;
  int lk = lane >> 4;
  int sx = lm & 7;
  f32x4 zero4 = {0.f,0.f,0.f,0.f};
  f32x4 acc[4][4];
  #pragma unroll
  for(int i=0;i<4;i++)
    #pragma unroll
    for(int j=0;j<4;j++) acc[i][j] = zero4;
  // prologue: stage t=0 into buf 0
  #pragma unroll
  for(int i=0;i<4;i++){
    int c = i*256 + tid, r = c >> 3, kc = c & 7;
    int kg = kc ^ (r & 7);
    gl2lds16(&A [(size_t)(m0 + r)*1024 + kg*8], &smem[c*8]);
    gl2lds16(&Bw[(size_t)(n0 + r)*1024 + kg*8], &smem[8192 + c*8]);
  }
  int cur = 0;
  for(int t=0; t<16; ++t){
    if(t < 15){
      int k0n = (t+1)*64;
      ushort_t* Ad = &smem[(cur^1)*16384];
      ushort_t* Bd = &smem[(cur^1)*16384 + 8192];
      #pragma unroll
      for(int i=0;i<4;i++){
        int c = i*256 + tid, r = c >> 3, kc = c & 7;
        int kg = kc ^ (r & 7);
        gl2lds16(&A [(size_t)(m0 + r)*1024 + k0n + kg*8], &Ad[c*8]);
        gl2lds16(&Bw[(size_t)(n0 + r)*1024 + k0n + kg*8], &Bd[c*8]);
      }
      asm volatile("s_waitcnt vmcnt(8)" ::: "memory");
    } else {
      asm volatile("s_waitcnt vmcnt(0)" ::: "memory");
    }
    __builtin_amdgcn_sched_barrier(0);
    __builtin_amdgcn_s_barrier();
    const ushort_t* As = &smem[cur*16384];
    const ushort_t* Bs = &smem[cur*16384 + 8192];
    #pragma unroll
    for(int kk=0; kk<64; kk+=32){
      short8 af[4], bf[4];
      int ch = ((kk >> 3) + lk) ^ sx;
      #pragma unroll
      for(int i=0;i<4;i++){
        af[i] = *(const short8*)&As[(wm + i*16 + lm)*64 + ch*8];
        bf[i] = *(const short8*)&Bs[(wn + i*16 + lm)*64 + ch*8];
      }
      #pragma unroll
      for(int i=0;i<4;i++)
        #pragma unroll
        for(int j=0;j<4;j++)
          acc[i][j] = __builtin_amdgcn_mfma_f32_16x16x32_bf16(af[i], bf[j], acc[i][j], 0, 0, 0);
    }
    __builtin_amdgcn_s_barrier();
    cur ^= 1;
  }
  // epilogue: LDS transpose, 32-n groups, coalesced float4 stores along l(=m)
  float* T = (float*)smem;               // [32][132] fp32 = 16,896 B
  int b = m0 >> 12, l0 = m0 & 4095;
  for(int g=0; g<4; ++g){
    __syncthreads();
    if((g >> 1) == (wave & 1)){
      int jg = g & 1;
      #pragma unroll
      for(int j2=0;j2<2;j2++){
        int j = jg*2 + j2;
        #pragma unroll
        for(int i=0;i<4;i++)
          #pragma unroll
          for(int r=0;r<4;r++){
            int ml = wm + i*16 + lk*4 + r;
            int nl = wn + j*16 + lm - g*32;
            T[nl*132 + ml] = acc[i][j][r];
          }
      }
    }
    __syncthreads();
    int nl = tid >> 3, seg = tid & 7;
    float* dst = &out[((size_t)b*DIM + n0 + g*32 + nl)*LEN + l0 + seg*16];
    #pragma unroll
    for(int k=0;k<4;k++){
      float4 v = *(const float4*)&T[nl*132 + seg*16 + k*4];
      *(float4*)&dst[k*4] = v;
    }
  }
}

extern "C" void kernel_launch(void* const* d_in, const int* in_sizes, int n_in,
                              void* d_out, int out_size, void* d_ws, size_t ws_size,
                              hipStream_t stream) {
  const float* x    = (const float*)d_in[0];
  const float* lnw  = (const float*)d_in[1];
  const float* lnb  = (const float*)d_in[2];
  const float* Win  = (const float*)d_in[3];
  const float* cw   = (const float*)d_in[4];
  const float* cb   = (const float*)d_in[5];
  const float* Wxp  = (const float*)d_in[6];
  const float* Wdt  = (const float*)d_in[7];
  const float* bdt  = (const float*)d_in[8];
  const float* Alog = (const float*)d_in[9];
  const float* Dp   = (const float*)d_in[10];
  const float* Wout = (const float*)d_in[11];
  float* out = (float*)d_out;
  float* ws  = (float*)d_ws;

  // workspace layout (float-slot offsets), total 147.25 MiB — no overlapping live ranges
  float*    mu   = ws;                          // 16384
  float*    rs   = ws + 16384;                  // 16384
  _Float16* xin  = (_Float16*)(ws + 32768);     // fp16, 16,777,216 halves (live gemm1..conv)
  _Float16* dF   = (_Float16*)(ws + 32768);     // same region, disjoint lifetime (deltag..scanC)
  float*    E    = ws + 32768 + 8388608;        // 4,194,304 fl (Hs in-place)
  float*    cum  = ws + 32768 + 12582912;       // 262,144 fl
  ushort_t* sz   = (ushort_t*)(ws + 32768 + 16777216);            // bf16 16,777,216
  ushort_t* u    = (ushort_t*)(ws + 32768 + 16777216 + 8388608);  // bf16 16,777,216 (y overwrites)
  ushort_t* xnT  = (ushort_t*)(ws + 32768 + 16777216 + 16777216); // bf16 8,388,608
  float*    dbl  = (float*)xnT;                 // alias after gemm1: 1,048,576 fp32
  ushort_t* Winb = (ushort_t*)(ws + 32768 + 16777216 + 16777216 + 4194304);
  ushort_t* Woutb= Winb + 1048576;
  ushort_t* Wxpb = Woutb + 524288;

  hipLaunchKernelGGL(prep_k,     dim3(1856),    dim3(1024), 0, stream, Win, Wout, Wxp, Winb, Woutb, Wxpb, x, mu, rs);
  hipLaunchKernelGGL(xnt_k,      dim3(2048),    dim3(256), 0, stream, x, mu, rs, lnw, lnb, xnT);
  hipLaunchKernelGGL(gemm1_mfma, dim3(16,128),  dim3(256), 0, stream, xnT, Winb, xin, sz);
  hipLaunchKernelGGL(conv_silu_k,dim3(1024),    dim3(256), 0, stream, xin, cw, cb, u);
  hipLaunchKernelGGL(gemm2_mfma, dim3(256),     dim3(256), 0, stream, u, Wxpb, dbl);
  hipLaunchKernelGGL(deltag_k,   dim3(1024),    dim3(256), 0, stream, dbl, Wdt, bdt, dF);
  hipLaunchKernelGGL(scanA_k,    dim3(1024),    dim3(256), 0, stream, u, dbl, Alog, dF, E, cum);
  hipLaunchKernelGGL(scanB_k,    dim3(256),     dim3(256), 0, stream, cum, Alog, E);
  hipLaunchKernelGGL(scanC_k,    dim3(1024),    dim3(256), 0, stream, u, dbl, Alog, E, Dp, sz, dF);
  hipLaunchKernelGGL(gemm4_mfma, dim3(4,128),   dim3(256), 0, stream, u, Woutb, out);
}

// Round 9
// 346.773 us; speedup vs baseline: 1.0676x; 1.0062x over previous
//
#include <hip/hip_runtime.h>
#include <math.h>

#define Bsz 4
#define DIM 512
#define LEN 4096
#define DST 16
#define DIN 1024
#define NCH 64    // chunks over L
#define CHL 64    // chunk length

typedef unsigned short ushort_t;
typedef unsigned int uint_t;
typedef __attribute__((ext_vector_type(8))) short short8;          // 8 bf16 (4 VGPRs)
typedef __attribute__((ext_vector_type(8))) unsigned short ushort8;
typedef __attribute__((ext_vector_type(8))) _Float16 half8;        // 8 fp16
typedef __attribute__((ext_vector_type(4))) float f32x4;

__device__ __forceinline__ float sigmoidf_(float x){ return 1.0f/(1.0f+__expf(-x)); }
__device__ __forceinline__ float bf2f(ushort_t u){ return __uint_as_float(((uint_t)u) << 16); }
__device__ __forceinline__ ushort_t f2bf(float f){
  uint_t x = __float_as_uint(f);
  uint_t r = (x + 0x7FFFu + ((x >> 16) & 1u)) >> 16;
  return (ushort_t)r;
}
__device__ __forceinline__ ushort_t f2h_bits(float f){
  _Float16 h = (_Float16)f;
  union { _Float16 h; ushort_t u; } v; v.h = h; return v.u;
}
__device__ __forceinline__ void gl2lds16(const void* g, void* l){
  __builtin_amdgcn_global_load_lds((const __attribute__((address_space(1))) void*)g,
                                   (__attribute__((address_space(3))) void*)l, 16, 0, 0);
}
// a^1..a^16 from a1=exp(-dv), log-depth
#define POW_CHAIN(av, a1) \
  { float a2=a1*a1, a4=a2*a2, a8=a4*a4; \
    av[0]=a1; av[1]=a2; av[2]=a2*a1; av[3]=a4; \
    av[4]=a4*a1; av[5]=a4*a2; av[6]=a4*av[2]; av[7]=a8; \
    av[8]=a8*a1; av[9]=a8*a2; av[10]=a8*av[2]; av[11]=a8*a4; \
    av[12]=a8*av[4]; av[13]=a8*av[5]; av[14]=a8*av[6]; av[15]=a8*a8; }

__device__ __forceinline__ bool load_nA(const float* Alog, int d, float* nA){
  bool fast = true;
  #pragma unroll
  for(int s=0;s<DST;s++){
    float v = -__expf(Alog[d*DST+s]);
    float tgt = -(float)(s+1);
    if(fabsf(v - tgt) < 1e-4f*(float)(s+1)) v = tgt;
    else fast = false;
    nA[s] = v;
  }
  return fast;
}

// ---------------- prep: weights->bf16 (blocks 0..1599) + LN stats @16 waves (blocks 1600..1855) ----
__global__ __launch_bounds__(1024) void prep_k(const float* __restrict__ Win,
    const float* __restrict__ Wout, const float* __restrict__ Wxp,
    ushort_t* __restrict__ Winb, ushort_t* __restrict__ Woutb, ushort_t* __restrict__ Wxpb,
    const float* __restrict__ x, float* __restrict__ mu, float* __restrict__ rs){
  __shared__ float rsum[16][64], rsq[16][64];
  int bid = blockIdx.x;
  int tid = threadIdx.x;
  if(bid < 1600){
    int i = bid*1024 + tid;
    if(i < 1048576) Winb[i] = f2bf(Win[i]);
    else if(i < 1572864) Woutb[i-1048576] = f2bf(Wout[i-1048576]);
    else Wxpb[i-1572864] = f2bf(Wxp[i-1572864]);
    return;
  }
  int sid = bid - 1600;        // 0..255
  int b = sid >> 6;
  int lg = sid & 63;
  int lane = tid & 63;
  int dgrp = tid >> 6;         // 0..15
  int l = lg*64 + lane;
  const float* xb = x + (size_t)b*DIM*LEN + l;
  float s = 0.f, sq = 0.f;
  #pragma unroll 8
  for(int i=0;i<32;i++){
    int d = dgrp*32 + i;
    float v = xb[(size_t)d*LEN];
    s += v; sq += v*v;
  }
  rsum[dgrp][lane] = s; rsq[dgrp][lane] = sq;
  __syncthreads();
  if(tid < 64){
    float ts = 0.f, tq = 0.f;
    #pragma unroll
    for(int g=0; g<16; ++g){ ts += rsum[g][tid]; tq += rsq[g][tid]; }
    float m = ts * (1.0f/DIM);
    float var = tq * (1.0f/DIM) - m*m;
    mu[b*LEN + lg*64 + tid] = m;
    rs[b*LEN + lg*64 + tid] = rsqrtf(var + 1e-5f);
  }
}

// ---------------- LN apply + transpose -> xnT bf16 [B*L][512] ----------------
__global__ __launch_bounds__(256) void xnt_k(const float* __restrict__ x,
    const float* __restrict__ mu, const float* __restrict__ rs,
    const float* __restrict__ lnw, const float* __restrict__ lnb, ushort_t* __restrict__ xnT){
  __shared__ ushort_t t[64][72];
  int bid = blockIdx.x;              // 4 * 8 * 64 = 2048
  int lt = bid & 63;
  int dt_ = (bid >> 6) & 7;
  int b = bid >> 9;
  int l0 = lt*64, d0 = dt_*64;
  int ll = threadIdx.x & 63;
  int dq = threadIdx.x >> 6;
  float mul_ = mu[b*LEN + l0 + ll], rsl = rs[b*LEN + l0 + ll];
  const float* xb = x + (size_t)b*DIM*LEN;
  #pragma unroll
  for(int i=0;i<16;i++){
    int d = d0 + dq*16 + i;
    float v = xb[(size_t)d*LEN + l0 + ll];
    t[ll][dq*16 + i] = f2bf((v - mul_)*rsl*lnw[d] + lnb[d]);
  }
  __syncthreads();
  int lr = threadIdx.x >> 2, seg = threadIdx.x & 3;
  ushort_t* dst = &xnT[(size_t)(b*LEN + l0 + lr)*DIM + d0 + seg*16];
  #pragma unroll
  for(int k=0;k<4;k++){
    ushort4 v = *(const ushort4*)&t[lr][seg*16 + k*4];
    *(ushort4*)&dst[k*4] = v;
  }
}

// ---------------- GEMM1 MFMA v8: 8-phase (T3+T4+T5) 256x256 tile, ring-4 k-half slots ----------
// xnT[16384][512] x Winb[2048][512] -> xin fp16 (n<1024) / sz bf16 (n>=1024)
// 16 k-halves of 32; ring of 4 LDS slots (32KB each): [256 rows][8 chunks of 16B] with A in
// logical chunks 0-3, B in 4-7, XOR-swizzled (chunk' = chunk ^ (row&7)) via pre-swizzled
// global source (rule #21). Staging runs 3 k-halves ahead; counted vmcnt (8/8/4/0 tail) —
// never drains in steady state. Per phase: {ds_read frags || 2 stage loads} -> s_barrier ->
// lgkmcnt(0)+sched_barrier (rule #18) -> setprio(1) + 16 MFMA + setprio(0) -> barrier.
#define G1_SLOT 16384   // ushorts per slot (32 KB)
__global__ __launch_bounds__(512) void gemm1_mfma(const ushort_t* __restrict__ A,
    const ushort_t* __restrict__ Bw, _Float16* __restrict__ xin, ushort_t* __restrict__ sz){
  __shared__ __align__(16) ushort_t smem[4*G1_SLOT];   // 128 KiB
  int tid = threadIdx.x;
  int wave = tid >> 6, lane = tid & 63;
  // XCD swizzle: 512 blocks -> 64 contiguous per XCD
  int flat = blockIdx.x;
  int orig = (flat & 7) * 64 + (flat >> 3);
  int n0 = (orig & 7) * 256;       // 8 n-tiles
  int m0 = (orig >> 3) * 256;      // 64 m-tiles
  int wm = wave >> 1;              // 0..3  (m quarter, 64 rows)
  int wn = wave & 1;               // 0..1  (n half, 128 cols)
  int lm = lane & 15, lk = lane >> 4;
  f32x4 zero4 = {0.f,0.f,0.f,0.f};
  f32x4 acc[4][8];
  #pragma unroll
  for(int i=0;i<4;i++)
    #pragma unroll
    for(int n=0;n<8;n++) acc[i][n] = zero4;

  // stage load ld (0..3) of k-half j: 512 thr x 16B = 64 rows x 128B
  auto STG = [&](int j, int ld){
    int slot = j & 3;
    int r = ld*64 + (tid >> 3);
    int p = tid & 7;
    int lgc = p ^ (r & 7);                 // logical chunk stored at physical p
    const ushort_t* src = (lgc < 4)
      ? &A [(size_t)(m0 + r)*512 + j*32 + lgc*8]
      : &Bw[(size_t)(n0 + r)*512 + j*32 + (lgc-4)*8];
    gl2lds16(src, &smem[slot*G1_SLOT + ld*4096 + tid*8]);
  };

  // prologue: stage k-halves 0,1,2 (12 loads); land slot 0
  #pragma unroll
  for(int jj=0; jj<3; ++jj)
    #pragma unroll
    for(int ld=0; ld<4; ++ld) STG(jj, ld);
  asm volatile("s_waitcnt vmcnt(8)" ::: "memory");
  __builtin_amdgcn_sched_barrier(0);
  __builtin_amdgcn_s_barrier();

  short8 af[4], bf[4];
  for(int j=0; j<16; ++j){
    const ushort_t* S = &smem[(j & 3)*G1_SLOT];
    // ---- phase 0: af (all m-frags) + bf n-half 0 ----
    #pragma unroll
    for(int i=0;i<4;i++){
      int r = wm*64 + i*16 + lm;
      af[i] = *(const short8*)&S[r*64 + (lk ^ (r & 7))*8];
    }
    #pragma unroll
    for(int i=0;i<4;i++){
      int r = wn*128 + i*16 + lm;
      bf[i] = *(const short8*)&S[r*64 + (((lk+4) ^ (r & 7)))*8];
    }
    if(j < 13){ STG(j+3, 0); STG(j+3, 1); }
    __builtin_amdgcn_s_barrier();
    asm volatile("s_waitcnt lgkmcnt(0)" ::: "memory");
    __builtin_amdgcn_sched_barrier(0);
    __builtin_amdgcn_s_setprio(1);
    #pragma unroll
    for(int i=0;i<4;i++)
      #pragma unroll
      for(int n=0;n<4;n++)
        acc[i][n] = __builtin_amdgcn_mfma_f32_16x16x32_bf16(af[i], bf[n], acc[i][n], 0, 0, 0);
    __builtin_amdgcn_s_setprio(0);
    __builtin_amdgcn_s_barrier();
    // ---- phase 1: bf n-half 1 (af persists) ----
    #pragma unroll
    for(int i=0;i<4;i++){
      int r = wn*128 + 64 + i*16 + lm;
      bf[i] = *(const short8*)&S[r*64 + (((lk+4) ^ (r & 7)))*8];
    }
    if(j < 13){ STG(j+3, 2); STG(j+3, 3); }
    __builtin_amdgcn_s_barrier();
    asm volatile("s_waitcnt lgkmcnt(0)" ::: "memory");
    __builtin_amdgcn_sched_barrier(0);
    __builtin_amdgcn_s_setprio(1);
    #pragma unroll
    for(int i=0;i<4;i++)
      #pragma unroll
      for(int n=0;n<4;n++)
        acc[i][4+n] = __builtin_amdgcn_mfma_f32_16x16x32_bf16(af[i], bf[n], acc[i][4+n], 0, 0, 0);
    __builtin_amdgcn_s_setprio(0);
    // counted wait: guarantee k-half j+1 landed before next pair (block-wide via barrier)
    if(j <= 12)      asm volatile("s_waitcnt vmcnt(8)" ::: "memory");
    else if(j == 13) asm volatile("s_waitcnt vmcnt(4)" ::: "memory");
    else if(j == 14) asm volatile("s_waitcnt vmcnt(0)" ::: "memory");
    __builtin_amdgcn_sched_barrier(0);
    __builtin_amdgcn_s_barrier();
  }
  // epilogue: 4 m-groups of 64 rows; T ushort [64][264]; coalesced 16B stores
  ushort_t* T = smem;
  bool is_z = (n0 >= 1024);
  for(int g=0; g<4; ++g){
    __syncthreads();
    if(wm == g){
      #pragma unroll
      for(int i=0;i<4;i++)
        #pragma unroll
        for(int n=0;n<8;n++)
          #pragma unroll
          for(int r=0;r<4;r++){
            int ml = i*16 + lk*4 + r;          // 0..63
            int nl = wn*128 + n*16 + lm;       // 0..255
            float v = acc[i][n][r];
            T[ml*264 + nl] = is_z ? f2bf(v * sigmoidf_(v)) : f2h_bits(v);
          }
    }
    __syncthreads();
    int row = tid >> 3, cs = (tid & 7)*8;
    #pragma unroll
    for(int k=0;k<4;k++){
      int col = cs + k*64;
      ushort8 v = *(const ushort8*)&T[row*264 + col];
      int gm = m0 + g*64 + row;
      if(!is_z) *(ushort8*)((ushort_t*)xin + (size_t)gm*DIN + n0 + col) = v;
      else      *(ushort8*)&sz[(size_t)gm*DIN + (n0-1024) + col] = v;
    }
  }
}

// ---------------- conv1d + SiLU -> u bf16 (streaming: 8 d x 8 l per thread) ----------------
__global__ __launch_bounds__(256) void conv_silu_k(const _Float16* __restrict__ xin,
    const float* __restrict__ cw, const float* __restrict__ cb, ushort_t* __restrict__ u){
  int idx = blockIdx.x*256 + threadIdx.x;   // 262,144 threads: (b, lc, dg)
  int dg = idx & 127;
  int lc = (idx >> 7) & 511;                // 512 chunks of 8 l
  int b  = idx >> 16;
  int d0 = dg*8;
  int l0 = lc*8;
  float bias[8];
  #pragma unroll
  for(int k=0;k<8;k+=4){
    float4 c4 = *(const float4*)&cb[d0+k];
    bias[k]=c4.x; bias[k+1]=c4.y; bias[k+2]=c4.z; bias[k+3]=c4.w;
  }
  float w[8][4];
  #pragma unroll
  for(int k=0;k<8;k++){
    float4 c4 = *(const float4*)&cw[(d0+k)*4];
    w[k][0]=c4.x; w[k][1]=c4.y; w[k][2]=c4.z; w[k][3]=c4.w;
  }
  const _Float16* base = xin + ((size_t)b*LEN)*DIN + d0;
  ushort_t* ub = u + ((size_t)b*LEN)*DIN + d0;
  float f0[8], f1[8], f2[8];
  if(lc > 0){
    half8 h0 = *(const half8*)&base[(size_t)(l0-3)*DIN];
    half8 h1 = *(const half8*)&base[(size_t)(l0-2)*DIN];
    half8 h2 = *(const half8*)&base[(size_t)(l0-1)*DIN];
    #pragma unroll
    for(int k=0;k<8;k++){ f0[k]=(float)h0[k]; f1[k]=(float)h1[k]; f2[k]=(float)h2[k]; }
  } else {
    #pragma unroll
    for(int k=0;k<8;k++){ f0[k]=0.f; f1[k]=0.f; f2[k]=0.f; }
  }
  #pragma unroll
  for(int t=0;t<8;t++){
    half8 xv = *(const half8*)&base[(size_t)(l0+t)*DIN];
    float f3[8];
    #pragma unroll
    for(int k=0;k<8;k++) f3[k] = (float)xv[k];
    short8 o;
    #pragma unroll
    for(int k=0;k<8;k++){
      float a = bias[k] + f0[k]*w[k][0] + f1[k]*w[k][1] + f2[k]*w[k][2] + f3[k]*w[k][3];
      float v = a * sigmoidf_(a);
      o[k] = (short)f2bf(v);
    }
    *(short8*)&ub[(size_t)(l0+t)*DIN] = o;
    #pragma unroll
    for(int k=0;k<8;k++){ f0[k]=f1[k]; f1[k]=f2[k]; f2[k]=f3[k]; }
  }
}

// ---------------- GEMM2 MFMA v3: BM=64 (256 blocks, full CU coverage) + counted vmcnt ----------
__global__ __launch_bounds__(256) void gemm2_mfma(const ushort_t* __restrict__ A,
    const ushort_t* __restrict__ Bw, float* __restrict__ dbl){
  __shared__ __align__(16) ushort_t smem[2*8192];   // 2 bufs x (As 4096 + Bs 4096) = 32 KiB
  int tid = threadIdx.x;
  int wave = tid >> 6, lane = tid & 63;
  int m0 = blockIdx.x * 64;
  int wm = (wave >> 1) * 32, wn = (wave & 1) * 32;
  int lm = lane & 15;
  int lk = lane >> 4;
  int sx = lm & 7;
  f32x4 zero4 = {0.f,0.f,0.f,0.f};
  f32x4 acc[2][2];
  #pragma unroll
  for(int i=0;i<2;i++){ acc[i][0] = zero4; acc[i][1] = zero4; }
  #pragma unroll
  for(int i=0;i<2;i++){
    int c = i*256 + tid, r = c >> 3, kc = c & 7;
    int kg = kc ^ (r & 7);
    gl2lds16(&A [(size_t)(m0 + r)*1024 + kg*8], &smem[c*8]);
    gl2lds16(&Bw[(size_t)r*1024 + kg*8], &smem[4096 + c*8]);
  }
  int cur = 0;
  for(int t=0; t<16; ++t){
    if(t < 15){
      int k0n = (t+1)*64;
      ushort_t* Ad = &smem[(cur^1)*8192];
      ushort_t* Bd = &smem[(cur^1)*8192 + 4096];
      #pragma unroll
      for(int i=0;i<2;i++){
        int c = i*256 + tid, r = c >> 3, kc = c & 7;
        int kg = kc ^ (r & 7);
        gl2lds16(&A [(size_t)(m0 + r)*1024 + k0n + kg*8], &Ad[c*8]);
        gl2lds16(&Bw[(size_t)r*1024 + k0n + kg*8], &Bd[c*8]);
      }
      asm volatile("s_waitcnt vmcnt(4)" ::: "memory");
    } else {
      asm volatile("s_waitcnt vmcnt(0)" ::: "memory");
    }
    __builtin_amdgcn_sched_barrier(0);
    __builtin_amdgcn_s_barrier();
    const ushort_t* As = &smem[cur*8192];
    const ushort_t* Bs = &smem[cur*8192 + 4096];
    #pragma unroll
    for(int kk=0; kk<64; kk+=32){
      short8 af[2], bf[2];
      int ch = ((kk >> 3) + lk) ^ sx;
      #pragma unroll
      for(int i=0;i<2;i++) af[i] = *(const short8*)&As[(wm + i*16 + lm)*64 + ch*8];
      #pragma unroll
      for(int j=0;j<2;j++) bf[j] = *(const short8*)&Bs[(wn + j*16 + lm)*64 + ch*8];
      #pragma unroll
      for(int i=0;i<2;i++)
        #pragma unroll
        for(int j=0;j<2;j++)
          acc[i][j] = __builtin_amdgcn_mfma_f32_16x16x32_bf16(af[i], bf[j], acc[i][j], 0, 0, 0);
    }
    __builtin_amdgcn_s_barrier();
    cur ^= 1;
  }
  #pragma unroll
  for(int i=0;i<2;i++)
    #pragma unroll
    for(int j=0;j<2;j++)
      #pragma unroll
      for(int r=0;r<4;r++){
        int m = m0 + wm + i*16 + lk*4 + r;
        int n = wn + j*16 + lm;
        dbl[(size_t)m*64 + n] = acc[i][j][r];
      }
}

// ---------------- deltag: dv[m,d] = softplus(dbl[m,0:32]·Wdt[d,:]+bdt[d]) -> fp16 ----------------
__global__ __launch_bounds__(256,4) void deltag_k(const float* __restrict__ dbl,
    const float* __restrict__ Wdt, const float* __restrict__ bdt,
    _Float16* __restrict__ dF){
  __shared__ __align__(16) float dts[64*32];
  int bid = blockIdx.x;              // 256 m-tiles x 4 d-tiles = 1024
  int d0 = (bid & 3) * 256;
  int m0 = (bid >> 2) * 64;
  int tid = threadIdx.x;
  const f32x4* src4 = (const f32x4*)(dbl + (size_t)m0*64);
  f32x4* dst4 = (f32x4*)dts;
  for(int i=tid; i<64*8; i+=256){
    int row = i >> 3, q = i & 7;
    dst4[i] = src4[row*16 + q];
  }
  int d = d0 + tid;
  float w[32];
  #pragma unroll
  for(int k=0;k<32;k+=4){
    float4 t4 = *(const float4*)&Wdt[d*32+k];
    w[k]=t4.x; w[k+1]=t4.y; w[k+2]=t4.z; w[k+3]=t4.w;
  }
  float bd = bdt[d];
  __syncthreads();
  for(int m=0;m<64;m++){
    const float* row = dts + m*32;
    float dtv = bd;
    #pragma unroll
    for(int k=0;k<32;k+=4){
      f32x4 q = *(const f32x4*)&row[k];
      dtv += q.x*w[k] + q.y*w[k+1] + q.z*w[k+2] + q.w*w[k+3];
    }
    float dv = dtv > 15.f ? dtv : __logf(1.f + __expf(dtv));
    dF[(size_t)(m0+m)*DIN + d] = (_Float16)dv;
  }
}

// ---------------- scan phase A: per-chunk local end state + cumD ----------------
__global__ __launch_bounds__(256,4) void scanA_k(const ushort_t* __restrict__ u,
    const float* __restrict__ dbl, const float* __restrict__ Alog,
    const _Float16* __restrict__ dF,
    float* __restrict__ E, float* __restrict__ cum){
  __shared__ __align__(16) float dch[CHL*16];   // B cols
  int bid = blockIdx.x;            // NCH*4*Bsz = 1024
  int c = bid & (NCH-1);
  int dblk = (bid >> 6) & 3;
  int b = bid >> 8;
  int d = dblk*256 + threadIdx.x;
  const f32x4* src = (const f32x4*)(dbl + ((size_t)b*LEN + c*CHL)*64);
  f32x4* dst4 = (f32x4*)dch;
  for(int i=threadIdx.x; i<CHL*4; i+=256){
    int t = i >> 2, q = i & 3;
    dst4[i] = src[t*16 + 8 + q];
  }
  float nA[DST];
  bool fast = load_nA(Alog, d, nA);
  float Es[DST];
  #pragma unroll
  for(int s=0;s<DST;s++) Es[s] = 0.f;
  float cumD = 0.f;
  __syncthreads();
  const ushort_t*  uu = u  + ((size_t)b*LEN + c*CHL)*DIN + d;
  const _Float16*  pd = dF + ((size_t)b*LEN + c*CHL)*DIN + d;
  if(fast){
    for(int t=0;t<CHL;++t){
      float dv = (float)pd[(size_t)t*DIN];
      float uv = bf2f(uu[(size_t)t*DIN]);
      float du = dv*uv;
      cumD += dv;
      float a1 = __expf(-dv);
      float av[DST];
      POW_CHAIN(av, a1);
      const f32x4* r4 = (const f32x4*)(dch + t*16);
      f32x4 B0=r4[0], B1=r4[1], B2=r4[2], B3=r4[3];
      Es[0]=av[0]*Es[0]+du*B0.x;  Es[1]=av[1]*Es[1]+du*B0.y;
      Es[2]=av[2]*Es[2]+du*B0.z;  Es[3]=av[3]*Es[3]+du*B0.w;
      Es[4]=av[4]*Es[4]+du*B1.x;  Es[5]=av[5]*Es[5]+du*B1.y;
      Es[6]=av[6]*Es[6]+du*B1.z;  Es[7]=av[7]*Es[7]+du*B1.w;
      Es[8]=av[8]*Es[8]+du*B2.x;  Es[9]=av[9]*Es[9]+du*B2.y;
      Es[10]=av[10]*Es[10]+du*B2.z; Es[11]=av[11]*Es[11]+du*B2.w;
      Es[12]=av[12]*Es[12]+du*B3.x; Es[13]=av[13]*Es[13]+du*B3.y;
      Es[14]=av[14]*Es[14]+du*B3.z; Es[15]=av[15]*Es[15]+du*B3.w;
    }
  } else {
    for(int t=0;t<CHL;++t){
      float dv = (float)pd[(size_t)t*DIN];
      float uv = bf2f(uu[(size_t)t*DIN]);
      float du = dv*uv;
      cumD += dv;
      const float* row = dch + t*16;
      #pragma unroll
      for(int s=0;s<DST;s++){
        float a = __expf(dv*nA[s]);
        Es[s] = a*Es[s] + du*row[s];
      }
    }
  }
  size_t o = (size_t)(b*NCH + c)*DST*DIN + d;
  #pragma unroll
  for(int s=0;s<DST;s++) E[o + (size_t)s*DIN] = Es[s];
  cum[(size_t)(b*NCH + c)*DIN + d] = cumD;
}

// ---------------- scan phase B: combine chunk boundaries; Hs in-place over E ----------------
__global__ __launch_bounds__(256) void scanB_k(const float* __restrict__ cum,
    const float* __restrict__ Alog, float* __restrict__ E){
  int g = blockIdx.x*256 + threadIdx.x;   // 65536 = Bsz*DST*DIN
  int d = g & 1023;
  int s = (g >> 10) & 15;
  int b = g >> 14;
  float v = -__expf(Alog[d*DST + s]);
  float tgt = -(float)(s+1);
  float nA = (fabsf(v - tgt) < 1e-4f*(float)(s+1)) ? tgt : v;
  float h = 0.f;
  for(int c=0;c<NCH;c++){
    float p = __expf(cum[(size_t)(b*NCH + c)*DIN + d] * nA);
    size_t o = (size_t)((b*NCH + c)*DST + s)*DIN + d;
    float e = E[o];
    E[o] = h;
    h = p*h + e;
  }
}

// ---------------- scan phase C: replay, y=(scan+u*D)*sz, y bf16 over u ----------------
__global__ __launch_bounds__(256,4) void scanC_k(ushort_t* __restrict__ u,
    const float* __restrict__ dbl, const float* __restrict__ Alog,
    const float* __restrict__ Hs, const float* __restrict__ Dp, const ushort_t* __restrict__ sz,
    const _Float16* __restrict__ dF){
  __shared__ __align__(16) float dch[CHL*32];   // B,C cols
  int bid = blockIdx.x;
  int c = bid & (NCH-1);
  int dblk = (bid >> 6) & 3;
  int b = bid >> 8;
  int d = dblk*256 + threadIdx.x;
  const f32x4* src = (const f32x4*)(dbl + ((size_t)b*LEN + c*CHL)*64);
  f32x4* dst4 = (f32x4*)dch;
  for(int i=threadIdx.x; i<CHL*8; i+=256){
    int t = i >> 3, q = i & 7;
    dst4[i] = src[t*16 + 8 + q];
  }
  float nA[DST];
  bool fast = load_nA(Alog, d, nA);
  float h[DST];
  size_t ho = (size_t)(b*NCH + c)*DST*DIN + d;
  #pragma unroll
  for(int s=0;s<DST;s++) h[s] = Hs[ho + (size_t)s*DIN];
  float Dv = Dp[d];
  __syncthreads();
  ushort_t* uu = u + ((size_t)b*LEN + c*CHL)*DIN + d;
  const ushort_t* zz = sz + ((size_t)b*LEN + c*CHL)*DIN + d;
  const _Float16* pd = dF + ((size_t)b*LEN + c*CHL)*DIN + d;
  if(fast){
    for(int t=0;t<CHL;++t){
      float dv = (float)pd[(size_t)t*DIN];
      float uv = bf2f(uu[(size_t)t*DIN]);
      float du = dv*uv;
      float a1 = __expf(-dv);
      float av[DST];
      POW_CHAIN(av, a1);
      const f32x4* r4 = (const f32x4*)(dch + t*32);
      f32x4 B0=r4[0], B1=r4[1], B2=r4[2], B3=r4[3];
      f32x4 C0=r4[4], C1=r4[5], C2=r4[6], C3=r4[7];
      float y0, y1, y2, y3;
      h[0]=av[0]*h[0]+du*B0.x;  h[1]=av[1]*h[1]+du*B0.y;
      h[2]=av[2]*h[2]+du*B0.z;  h[3]=av[3]*h[3]+du*B0.w;
      y0 = h[0]*C0.x + h[1]*C0.y; y1 = h[2]*C0.z + h[3]*C0.w;
      h[4]=av[4]*h[4]+du*B1.x;  h[5]=av[5]*h[5]+du*B1.y;
      h[6]=av[6]*h[6]+du*B1.z;  h[7]=av[7]*h[7]+du*B1.w;
      y2 = h[4]*C1.x + h[5]*C1.y; y3 = h[6]*C1.z + h[7]*C1.w;
      h[8]=av[8]*h[8]+du*B2.x;  h[9]=av[9]*h[9]+du*B2.y;
      h[10]=av[10]*h[10]+du*B2.z; h[11]=av[11]*h[11]+du*B2.w;
      y0 += h[8]*C2.x + h[9]*C2.y; y1 += h[10]*C2.z + h[11]*C2.w;
      h[12]=av[12]*h[12]+du*B3.x; h[13]=av[13]*h[13]+du*B3.y;
      h[14]=av[14]*h[14]+du*B3.z; h[15]=av[15]*h[15]+du*B3.w;
      y2 += h[12]*C3.x + h[13]*C3.y; y3 += h[14]*C3.z + h[15]*C3.w;
      float y = (y0+y1) + (y2+y3) + uv*Dv;
      y *= bf2f(zz[(size_t)t*DIN]);
      uu[(size_t)t*DIN] = f2bf(y);
    }
  } else {
    for(int t=0;t<CHL;++t){
      float dv = (float)pd[(size_t)t*DIN];
      float uv = bf2f(uu[(size_t)t*DIN]);
      float du = dv*uv;
      const float* row = dch + t*32;
      float y = 0.f;
      #pragma unroll
      for(int s=0;s<DST;s++){
        float a = __expf(dv*nA[s]);
        h[s] = a*h[s] + du*row[s];
        y += h[s]*row[16+s];
      }
      y += uv*Dv;
      y *= bf2f(zz[(size_t)t*DIN]);
      uu[(size_t)t*DIN] = f2bf(y);
    }
  }
}

// ---------------- GEMM4 MFMA v6 (R4 best): dbuf gl2lds + counted vmcnt ----------------
__global__ __launch_bounds__(256) void gemm4_mfma(const ushort_t* __restrict__ A,
    const ushort_t* __restrict__ Bw, float* __restrict__ out){
  __shared__ __align__(16) ushort_t smem[2*16384];   // 64 KiB; epilogue reuses as float
  int tid = threadIdx.x;
  int wave = tid >> 6, lane = tid & 63;
  int flat = blockIdx.y * 4 + blockIdx.x;
  int orig = (flat & 7) * 64 + (flat >> 3);
  int n0 = (orig & 3) * 128;       // N=512 -> 4
  int m0 = (orig >> 2) * 128;
  int wm = (wave >> 1) * 64, wn = (wave & 1) * 64;
  int lm = lane & 15;
  int lk = lane >> 4;
  int sx = lm & 7;
  f32x4 zero4 = {0.f,0.f,0.f,0.f};
  f32x4 acc[4][4];
  #pragma unroll
  for(int i=0;i<4;i++)
    #pragma unroll
    for(int j=0;j<4;j++) acc[i][j] = zero4;
  #pragma unroll
  for(int i=0;i<4;i++){
    int c = i*256 + tid, r = c >> 3, kc = c & 7;
    int kg = kc ^ (r & 7);
    gl2lds16(&A [(size_t)(m0 + r)*1024 + kg*8], &smem[c*8]);
    gl2lds16(&Bw[(size_t)(n0 + r)*1024 + kg*8], &smem[8192 + c*8]);
  }
  int cur = 0;
  for(int t=0; t<16; ++t){
    if(t < 15){
      int k0n = (t+1)*64;
      ushort_t* Ad = &smem[(cur^1)*16384];
      ushort_t* Bd = &smem[(cur^1)*16384 + 8192];
      #pragma unroll
      for(int i=0;i<4;i++){
        int c = i*256 + tid, r = c >> 3, kc = c & 7;
        int kg = kc ^ (r & 7);
        gl2lds16(&A [(size_t)(m0 + r)*1024 + k0n + kg*8], &Ad[c*8]);
        gl2lds16(&Bw[(size_t)(n0 + r)*1024 + k0n + kg*8], &Bd[c*8]);
      }
      asm volatile("s_waitcnt vmcnt(8)" ::: "memory");
    } else {
      asm volatile("s_waitcnt vmcnt(0)" ::: "memory");
    }
    __builtin_amdgcn_sched_barrier(0);
    __builtin_amdgcn_s_barrier();
    const ushort_t* As = &smem[cur*16384];
    const ushort_t* Bs = &smem[cur*16384 + 8192];
    #pragma unroll
    for(int kk=0; kk<64; kk+=32){
      short8 af[4], bf[4];
      int ch = ((kk >> 3) + lk) ^ sx;
      #pragma unroll
      for(int i=0;i<4;i++){
        af[i] = *(const short8*)&As[(wm + i*16 + lm)*64 + ch*8];
        bf[i] = *(const short8*)&Bs[(wn + i*16 + lm)*64 + ch*8];
      }
      #pragma unroll
      for(int i=0;i<4;i++)
        #pragma unroll
        for(int j=0;j<4;j++)
          acc[i][j] = __builtin_amdgcn_mfma_f32_16x16x32_bf16(af[i], bf[j], acc[i][j], 0, 0, 0);
    }
    __builtin_amdgcn_s_barrier();
    cur ^= 1;
  }
  float* T = (float*)smem;               // [32][132] fp32 = 16,896 B
  int b = m0 >> 12, l0 = m0 & 4095;
  for(int g=0; g<4; ++g){
    __syncthreads();
    if((g >> 1) == (wave & 1)){
      int jg = g & 1;
      #pragma unroll
      for(int j2=0;j2<2;j2++){
        int j = jg*2 + j2;
        #pragma unroll
        for(int i=0;i<4;i++)
          #pragma unroll
          for(int r=0;r<4;r++){
            int ml = wm + i*16 + lk*4 + r;
            int nl = wn + j*16 + lm - g*32;
            T[nl*132 + ml] = acc[i][j][r];
          }
      }
    }
    __syncthreads();
    int nl = tid >> 3, seg = tid & 7;
    float* dst = &out[((size_t)b*DIM + n0 + g*32 + nl)*LEN + l0 + seg*16];
    #pragma unroll
    for(int k=0;k<4;k++){
      float4 v = *(const float4*)&T[nl*132 + seg*16 + k*4];
      *(float4*)&dst[k*4] = v;
    }
  }
}

extern "C" void kernel_launch(void* const* d_in, const int* in_sizes, int n_in,
                              void* d_out, int out_size, void* d_ws, size_t ws_size,
                              hipStream_t stream) {
  const float* x    = (const float*)d_in[0];
  const float* lnw  = (const float*)d_in[1];
  const float* lnb  = (const float*)d_in[2];
  const float* Win  = (const float*)d_in[3];
  const float* cw   = (const float*)d_in[4];
  const float* cb   = (const float*)d_in[5];
  const float* Wxp  = (const float*)d_in[6];
  const float* Wdt  = (const float*)d_in[7];
  const float* bdt  = (const float*)d_in[8];
  const float* Alog = (const float*)d_in[9];
  const float* Dp   = (const float*)d_in[10];
  const float* Wout = (const float*)d_in[11];
  float* out = (float*)d_out;
  float* ws  = (float*)d_ws;

  // workspace layout (float-slot offsets), total 147.25 MiB — no overlapping live ranges
  float*    mu   = ws;                          // 16384
  float*    rs   = ws + 16384;                  // 16384
  _Float16* xin  = (_Float16*)(ws + 32768);     // fp16, 16,777,216 halves (live gemm1..conv)
  _Float16* dF   = (_Float16*)(ws + 32768);     // same region, disjoint lifetime (deltag..scanC)
  float*    E    = ws + 32768 + 8388608;        // 4,194,304 fl (Hs in-place)
  float*    cum  = ws + 32768 + 12582912;       // 262,144 fl
  ushort_t* sz   = (ushort_t*)(ws + 32768 + 16777216);            // bf16 16,777,216
  ushort_t* u    = (ushort_t*)(ws + 32768 + 16777216 + 8388608);  // bf16 16,777,216 (y overwrites)
  ushort_t* xnT  = (ushort_t*)(ws + 32768 + 16777216 + 16777216); // bf16 8,388,608
  float*    dbl  = (float*)xnT;                 // alias after gemm1: 1,048,576 fp32
  ushort_t* Winb = (ushort_t*)(ws + 32768 + 16777216 + 16777216 + 4194304);
  ushort_t* Woutb= Winb + 1048576;
  ushort_t* Wxpb = Woutb + 524288;

  hipLaunchKernelGGL(prep_k,     dim3(1856),    dim3(1024), 0, stream, Win, Wout, Wxp, Winb, Woutb, Wxpb, x, mu, rs);
  hipLaunchKernelGGL(xnt_k,      dim3(2048),    dim3(256), 0, stream, x, mu, rs, lnw, lnb, xnT);
  hipLaunchKernelGGL(gemm1_mfma, dim3(512),     dim3(512), 0, stream, xnT, Winb, xin, sz);
  hipLaunchKernelGGL(conv_silu_k,dim3(1024),    dim3(256), 0, stream, xin, cw, cb, u);
  hipLaunchKernelGGL(gemm2_mfma, dim3(256),     dim3(256), 0, stream, u, Wxpb, dbl);
  hipLaunchKernelGGL(deltag_k,   dim3(1024),    dim3(256), 0, stream, dbl, Wdt, bdt, dF);
  hipLaunchKernelGGL(scanA_k,    dim3(1024),    dim3(256), 0, stream, u, dbl, Alog, dF, E, cum);
  hipLaunchKernelGGL(scanB_k,    dim3(256),     dim3(256), 0, stream, cum, Alog, E);
  hipLaunchKernelGGL(scanC_k,    dim3(1024),    dim3(256), 0, stream, u, dbl, Alog, E, Dp, sz, dF);
  hipLaunchKernelGGL(gemm4_mfma, dim3(4,128),   dim3(256), 0, stream, u, Woutb, out);
}

// Round 11
// 328.069 us; speedup vs baseline: 1.1285x; 1.0570x over previous
//
#include <hip/hip_runtime.h>
#include <math.h>

#define Bsz 4
#define DIM 512
#define LEN 4096
#define DST 16
#define DIN 1024
#define NCH 64    // chunks over L
#define CHL 64    // chunk length

typedef unsigned short ushort_t;
typedef unsigned int uint_t;
typedef __attribute__((ext_vector_type(8))) short short8;          // 8 bf16 (4 VGPRs)
typedef __attribute__((ext_vector_type(8))) unsigned short ushort8;
typedef __attribute__((ext_vector_type(8))) _Float16 half8;        // 8 fp16
typedef __attribute__((ext_vector_type(4))) float f32x4;

__device__ __forceinline__ float sigmoidf_(float x){ return 1.0f/(1.0f+__expf(-x)); }
__device__ __forceinline__ float bf2f(ushort_t u){ return __uint_as_float(((uint_t)u) << 16); }
__device__ __forceinline__ ushort_t f2bf(float f){
  uint_t x = __float_as_uint(f);
  uint_t r = (x + 0x7FFFu + ((x >> 16) & 1u)) >> 16;
  return (ushort_t)r;
}
__device__ __forceinline__ ushort_t f2h_bits(float f){
  _Float16 h = (_Float16)f;
  union { _Float16 h; ushort_t u; } v; v.h = h; return v.u;
}
__device__ __forceinline__ void gl2lds16(const void* g, void* l){
  __builtin_amdgcn_global_load_lds((const __attribute__((address_space(1))) void*)g,
                                   (__attribute__((address_space(3))) void*)l, 16, 0, 0);
}
// a^1..a^16 from a1=exp(-dv), log-depth
#define POW_CHAIN(av, a1) \
  { float a2=a1*a1, a4=a2*a2, a8=a4*a4; \
    av[0]=a1; av[1]=a2; av[2]=a2*a1; av[3]=a4; \
    av[4]=a4*a1; av[5]=a4*a2; av[6]=a4*av[2]; av[7]=a8; \
    av[8]=a8*a1; av[9]=a8*a2; av[10]=a8*av[2]; av[11]=a8*a4; \
    av[12]=a8*av[4]; av[13]=a8*av[5]; av[14]=a8*av[6]; av[15]=a8*a8; }

__device__ __forceinline__ bool load_nA(const float* Alog, int d, float* nA){
  bool fast = true;
  #pragma unroll
  for(int s=0;s<DST;s++){
    float v = -__expf(Alog[d*DST+s]);
    float tgt = -(float)(s+1);
    if(fabsf(v - tgt) < 1e-4f*(float)(s+1)) v = tgt;
    else fast = false;
    nA[s] = v;
  }
  return fast;
}

// ---------------- prep: weights->bf16 (blocks 0..1599) + LN stats @16 waves (blocks 1600..1855) ----
// wcvt part: 1600 blocks x 1024 threads = 1,638,400 elements exactly.
// stats part: 256 logical blocks, each 64 l-rows x 512 d with 1024 threads (16 waves/CU):
// lanes = consecutive l (256B coalesced), dgrp = wave index; 32 d per thread -> deep load ILP.
__global__ __launch_bounds__(1024) void prep_k(const float* __restrict__ Win,
    const float* __restrict__ Wout, const float* __restrict__ Wxp,
    ushort_t* __restrict__ Winb, ushort_t* __restrict__ Woutb, ushort_t* __restrict__ Wxpb,
    const float* __restrict__ x, float* __restrict__ mu, float* __restrict__ rs){
  __shared__ float rsum[16][64], rsq[16][64];
  int bid = blockIdx.x;
  int tid = threadIdx.x;
  if(bid < 1600){
    int i = bid*1024 + tid;
    if(i < 1048576) Winb[i] = f2bf(Win[i]);
    else if(i < 1572864) Woutb[i-1048576] = f2bf(Wout[i-1048576]);
    else Wxpb[i-1572864] = f2bf(Wxp[i-1572864]);
    return;
  }
  int sid = bid - 1600;        // 0..255
  int b = sid >> 6;
  int lg = sid & 63;
  int lane = tid & 63;
  int dgrp = tid >> 6;         // 0..15
  int l = lg*64 + lane;
  const float* xb = x + (size_t)b*DIM*LEN + l;
  float s = 0.f, sq = 0.f;
  #pragma unroll 8
  for(int i=0;i<32;i++){
    int d = dgrp*32 + i;
    float v = xb[(size_t)d*LEN];
    s += v; sq += v*v;
  }
  rsum[dgrp][lane] = s; rsq[dgrp][lane] = sq;
  __syncthreads();
  if(tid < 64){
    float ts = 0.f, tq = 0.f;
    #pragma unroll
    for(int g=0; g<16; ++g){ ts += rsum[g][tid]; tq += rsq[g][tid]; }
    float m = ts * (1.0f/DIM);
    float var = tq * (1.0f/DIM) - m*m;
    mu[b*LEN + lg*64 + tid] = m;
    rs[b*LEN + lg*64 + tid] = rsqrtf(var + 1e-5f);
  }
}

// ---------------- LN apply + transpose -> xnT bf16 [B*L][512] ----------------
__global__ __launch_bounds__(256) void xnt_k(const float* __restrict__ x,
    const float* __restrict__ mu, const float* __restrict__ rs,
    const float* __restrict__ lnw, const float* __restrict__ lnb, ushort_t* __restrict__ xnT){
  __shared__ ushort_t t[64][72];
  int bid = blockIdx.x;              // 4 * 8 * 64 = 2048
  int lt = bid & 63;
  int dt_ = (bid >> 6) & 7;
  int b = bid >> 9;
  int l0 = lt*64, d0 = dt_*64;
  int ll = threadIdx.x & 63;
  int dq = threadIdx.x >> 6;
  float mul_ = mu[b*LEN + l0 + ll], rsl = rs[b*LEN + l0 + ll];
  const float* xb = x + (size_t)b*DIM*LEN;
  #pragma unroll
  for(int i=0;i<16;i++){
    int d = d0 + dq*16 + i;
    float v = xb[(size_t)d*LEN + l0 + ll];
    t[ll][dq*16 + i] = f2bf((v - mul_)*rsl*lnw[d] + lnb[d]);
  }
  __syncthreads();
  int lr = threadIdx.x >> 2, seg = threadIdx.x & 3;
  ushort_t* dst = &xnT[(size_t)(b*LEN + l0 + lr)*DIM + d0 + seg*16];
  #pragma unroll
  for(int k=0;k<4;k++){
    ushort4 v = *(const ushort4*)&t[lr][seg*16 + k*4];
    *(ushort4*)&dst[k*4] = v;
  }
}

// ---------------- GEMM1 MFMA v6 (best verified): dbuf gl2lds + counted vmcnt ----------------
// xnT[16384][512] x Winb[2048][512] -> xin fp16 (n<1024) / sz bf16 (n>=1024)
__global__ __launch_bounds__(256) void gemm1_mfma(const ushort_t* __restrict__ A,
    const ushort_t* __restrict__ Bw, _Float16* __restrict__ xin, ushort_t* __restrict__ sz){
  __shared__ __align__(16) ushort_t smem[2*16384];   // 2 bufs x (As 8192 + Bs 8192) = 64 KiB
  int tid = threadIdx.x;
  int wave = tid >> 6, lane = tid & 63;
  // XCD-aware swizzle: 2048 blocks, 8 XCDs -> 256 contiguous tiles per XCD
  int flat = blockIdx.y * 16 + blockIdx.x;
  int orig = (flat & 7) * 256 + (flat >> 3);
  int n0 = (orig & 15) * 128;
  int m0 = (orig >> 4) * 128;
  int wm = (wave >> 1) * 64, wn = (wave & 1) * 64;
  int lm = lane & 15;
  int lk = lane >> 4;
  int sx = lm & 7;                     // read-side XOR key (row&7 == lm&7)
  f32x4 zero4 = {0.f,0.f,0.f,0.f};
  f32x4 acc[4][4];
  #pragma unroll
  for(int i=0;i<4;i++)
    #pragma unroll
    for(int j=0;j<4;j++) acc[i][j] = zero4;
  // prologue: stage t=0 into buf 0
  #pragma unroll
  for(int i=0;i<4;i++){
    int c = i*256 + tid, r = c >> 3, kc = c & 7;
    int kg = kc ^ (r & 7);
    gl2lds16(&A [(size_t)(m0 + r)*512 + kg*8], &smem[c*8]);
    gl2lds16(&Bw[(size_t)(n0 + r)*512 + kg*8], &smem[8192 + c*8]);
  }
  int cur = 0;
  for(int t=0; t<8; ++t){
    if(t < 7){
      int k0n = (t+1)*64;
      ushort_t* Ad = &smem[(cur^1)*16384];
      ushort_t* Bd = &smem[(cur^1)*16384 + 8192];
      #pragma unroll
      for(int i=0;i<4;i++){
        int c = i*256 + tid, r = c >> 3, kc = c & 7;
        int kg = kc ^ (r & 7);
        gl2lds16(&A [(size_t)(m0 + r)*512 + k0n + kg*8], &Ad[c*8]);
        gl2lds16(&Bw[(size_t)(n0 + r)*512 + k0n + kg*8], &Bd[c*8]);
      }
      asm volatile("s_waitcnt vmcnt(8)" ::: "memory");   // stage(t) landed; t+1 stays in flight
    } else {
      asm volatile("s_waitcnt vmcnt(0)" ::: "memory");   // final: drain stage(7)
    }
    __builtin_amdgcn_sched_barrier(0);
    __builtin_amdgcn_s_barrier();      // all waves: buf[cur] complete
    const ushort_t* As = &smem[cur*16384];
    const ushort_t* Bs = &smem[cur*16384 + 8192];
    #pragma unroll
    for(int kk=0; kk<64; kk+=32){
      short8 af[4], bf[4];
      int ch = ((kk >> 3) + lk) ^ sx;   // swizzled 16B-chunk index
      #pragma unroll
      for(int i=0;i<4;i++){
        af[i] = *(const short8*)&As[(wm + i*16 + lm)*64 + ch*8];
        bf[i] = *(const short8*)&Bs[(wn + i*16 + lm)*64 + ch*8];
      }
      #pragma unroll
      for(int i=0;i<4;i++)
        #pragma unroll
        for(int j=0;j<4;j++)
          acc[i][j] = __builtin_amdgcn_mfma_f32_16x16x32_bf16(af[i], bf[j], acc[i][j], 0, 0, 0);
    }
    __builtin_amdgcn_s_barrier();      // exec sync: next iter may overwrite buf[cur^1]
    cur ^= 1;
  }
  // epilogue: LDS transpose (ushort [128][136]) + coalesced 16B stores
  ushort_t* T = smem;                      // 128*136 = 17,408 ushorts <= 32,768
  bool is_z = (n0 >= 1024);
  #pragma unroll
  for(int i=0;i<4;i++)
    #pragma unroll
    for(int j=0;j<4;j++)
      #pragma unroll
      for(int r=0;r<4;r++){
        int ml = wm + i*16 + lk*4 + r;
        int nl = wn + j*16 + lm;
        float v = acc[i][j][r];
        T[ml*136 + nl] = is_z ? f2bf(v * sigmoidf_(v)) : f2h_bits(v);
      }
  __syncthreads();
  int rr = tid >> 4, cc = (tid & 15)*8;
  #pragma unroll
  for(int p=0;p<8;p++){
    int row = p*16 + rr;
    ushort8 v = *(const ushort8*)&T[row*136 + cc];
    if(!is_z) *(ushort8*)((ushort_t*)xin + (size_t)(m0+row)*DIN + n0 + cc) = v;
    else      *(ushort8*)&sz[(size_t)(m0+row)*DIN + (n0-1024) + cc] = v;
  }
}

// ---------------- conv1d + SiLU -> u bf16 (streaming: 8 d x 8 l per thread) ----------------
__global__ __launch_bounds__(256) void conv_silu_k(const _Float16* __restrict__ xin,
    const float* __restrict__ cw, const float* __restrict__ cb, ushort_t* __restrict__ u){
  int idx = blockIdx.x*256 + threadIdx.x;   // 262,144 threads: (b, lc, dg)
  int dg = idx & 127;
  int lc = (idx >> 7) & 511;                // 512 chunks of 8 l
  int b  = idx >> 16;
  int d0 = dg*8;
  int l0 = lc*8;
  float bias[8];
  #pragma unroll
  for(int k=0;k<8;k+=4){
    float4 c4 = *(const float4*)&cb[d0+k];
    bias[k]=c4.x; bias[k+1]=c4.y; bias[k+2]=c4.z; bias[k+3]=c4.w;
  }
  float w[8][4];
  #pragma unroll
  for(int k=0;k<8;k++){
    float4 c4 = *(const float4*)&cw[(d0+k)*4];
    w[k][0]=c4.x; w[k][1]=c4.y; w[k][2]=c4.z; w[k][3]=c4.w;
  }
  const _Float16* base = xin + ((size_t)b*LEN)*DIN + d0;
  ushort_t* ub = u + ((size_t)b*LEN)*DIN + d0;
  float f0[8], f1[8], f2[8];
  if(lc > 0){
    half8 h0 = *(const half8*)&base[(size_t)(l0-3)*DIN];
    half8 h1 = *(const half8*)&base[(size_t)(l0-2)*DIN];
    half8 h2 = *(const half8*)&base[(size_t)(l0-1)*DIN];
    #pragma unroll
    for(int k=0;k<8;k++){ f0[k]=(float)h0[k]; f1[k]=(float)h1[k]; f2[k]=(float)h2[k]; }
  } else {
    #pragma unroll
    for(int k=0;k<8;k++){ f0[k]=0.f; f1[k]=0.f; f2[k]=0.f; }
  }
  #pragma unroll
  for(int t=0;t<8;t++){
    half8 xv = *(const half8*)&base[(size_t)(l0+t)*DIN];
    float f3[8];
    #pragma unroll
    for(int k=0;k<8;k++) f3[k] = (float)xv[k];
    short8 o;
    #pragma unroll
    for(int k=0;k<8;k++){
      float a = bias[k] + f0[k]*w[k][0] + f1[k]*w[k][1] + f2[k]*w[k][2] + f3[k]*w[k][3];
      float v = a * sigmoidf_(a);
      o[k] = (short)f2bf(v);
    }
    *(short8*)&ub[(size_t)(l0+t)*DIN] = o;
    #pragma unroll
    for(int k=0;k<8;k++){ f0[k]=f1[k]; f1[k]=f2[k]; f2[k]=f3[k]; }
  }
}

// ---------------- GEMM2 MFMA v3: BM=64 (256 blocks, full CU coverage) + counted vmcnt ----------
// u[16384][1024] x Wxpb[64][1024] -> dbl fp32 [16384][64]
__global__ __launch_bounds__(256) void gemm2_mfma(const ushort_t* __restrict__ A,
    const ushort_t* __restrict__ Bw, float* __restrict__ dbl){
  __shared__ __align__(16) ushort_t smem[2*8192];   // 2 bufs x (As 4096 + Bs 4096) = 32 KiB
  int tid = threadIdx.x;
  int wave = tid >> 6, lane = tid & 63;
  int m0 = blockIdx.x * 64;
  int wm = (wave >> 1) * 32, wn = (wave & 1) * 32;
  int lm = lane & 15;
  int lk = lane >> 4;
  int sx = lm & 7;
  f32x4 zero4 = {0.f,0.f,0.f,0.f};
  f32x4 acc[2][2];
  #pragma unroll
  for(int i=0;i<2;i++){ acc[i][0] = zero4; acc[i][1] = zero4; }
  // prologue: stage t=0 into buf 0
  #pragma unroll
  for(int i=0;i<2;i++){
    int c = i*256 + tid, r = c >> 3, kc = c & 7;
    int kg = kc ^ (r & 7);
    gl2lds16(&A [(size_t)(m0 + r)*1024 + kg*8], &smem[c*8]);
    gl2lds16(&Bw[(size_t)r*1024 + kg*8], &smem[4096 + c*8]);
  }
  int cur = 0;
  for(int t=0; t<16; ++t){
    if(t < 15){
      int k0n = (t+1)*64;
      ushort_t* Ad = &smem[(cur^1)*8192];
      ushort_t* Bd = &smem[(cur^1)*8192 + 4096];
      #pragma unroll
      for(int i=0;i<2;i++){
        int c = i*256 + tid, r = c >> 3, kc = c & 7;
        int kg = kc ^ (r & 7);
        gl2lds16(&A [(size_t)(m0 + r)*1024 + k0n + kg*8], &Ad[c*8]);
        gl2lds16(&Bw[(size_t)r*1024 + k0n + kg*8], &Bd[c*8]);
      }
      asm volatile("s_waitcnt vmcnt(4)" ::: "memory");
    } else {
      asm volatile("s_waitcnt vmcnt(0)" ::: "memory");
    }
    __builtin_amdgcn_sched_barrier(0);
    __builtin_amdgcn_s_barrier();
    const ushort_t* As = &smem[cur*8192];
    const ushort_t* Bs = &smem[cur*8192 + 4096];
    #pragma unroll
    for(int kk=0; kk<64; kk+=32){
      short8 af[2], bf[2];
      int ch = ((kk >> 3) + lk) ^ sx;
      #pragma unroll
      for(int i=0;i<2;i++) af[i] = *(const short8*)&As[(wm + i*16 + lm)*64 + ch*8];
      #pragma unroll
      for(int j=0;j<2;j++) bf[j] = *(const short8*)&Bs[(wn + j*16 + lm)*64 + ch*8];
      #pragma unroll
      for(int i=0;i<2;i++)
        #pragma unroll
        for(int j=0;j<2;j++)
          acc[i][j] = __builtin_amdgcn_mfma_f32_16x16x32_bf16(af[i], bf[j], acc[i][j], 0, 0, 0);
    }
    __builtin_amdgcn_s_barrier();
    cur ^= 1;
  }
  #pragma unroll
  for(int i=0;i<2;i++)
    #pragma unroll
    for(int j=0;j<2;j++)
      #pragma unroll
      for(int r=0;r<4;r++){
        int m = m0 + wm + i*16 + lk*4 + r;
        int n = wn + j*16 + lm;
        dbl[(size_t)m*64 + n] = acc[i][j][r];
      }
}

// ---------------- deltag: dv[m,d] = softplus(dbl[m,0:32]·Wdt[d,:]+bdt[d]) -> fp16 ----------------
__global__ __launch_bounds__(256,4) void deltag_k(const float* __restrict__ dbl,
    const float* __restrict__ Wdt, const float* __restrict__ bdt,
    _Float16* __restrict__ dF){
  __shared__ __align__(16) float dts[64*32];
  int bid = blockIdx.x;              // 256 m-tiles x 4 d-tiles = 1024
  int d0 = (bid & 3) * 256;
  int m0 = (bid >> 2) * 64;
  int tid = threadIdx.x;
  const f32x4* src4 = (const f32x4*)(dbl + (size_t)m0*64);
  f32x4* dst4 = (f32x4*)dts;
  for(int i=tid; i<64*8; i+=256){
    int row = i >> 3, q = i & 7;
    dst4[i] = src4[row*16 + q];
  }
  int d = d0 + tid;
  float w[32];
  #pragma unroll
  for(int k=0;k<32;k+=4){
    float4 t4 = *(const float4*)&Wdt[d*32+k];
    w[k]=t4.x; w[k+1]=t4.y; w[k+2]=t4.z; w[k+3]=t4.w;
  }
  float bd = bdt[d];
  __syncthreads();
  for(int m=0;m<64;m++){
    const float* row = dts + m*32;
    float dtv = bd;
    #pragma unroll
    for(int k=0;k<32;k+=4){
      f32x4 q = *(const f32x4*)&row[k];
      dtv += q.x*w[k] + q.y*w[k+1] + q.z*w[k+2] + q.w*w[k+3];
    }
    float dv = dtv > 15.f ? dtv : __logf(1.f + __expf(dtv));
    dF[(size_t)(m0+m)*DIN + d] = (_Float16)dv;
  }
}

// ---------------- scan phase A: per-chunk local end state + cumD ----------------
__global__ __launch_bounds__(256,4) void scanA_k(const ushort_t* __restrict__ u,
    const float* __restrict__ dbl, const float* __restrict__ Alog,
    const _Float16* __restrict__ dF,
    float* __restrict__ E, float* __restrict__ cum){
  __shared__ __align__(16) float dch[CHL*16];   // B cols
  int bid = blockIdx.x;            // NCH*4*Bsz = 1024
  int c = bid & (NCH-1);
  int dblk = (bid >> 6) & 3;
  int b = bid >> 8;
  int d = dblk*256 + threadIdx.x;
  const f32x4* src = (const f32x4*)(dbl + ((size_t)b*LEN + c*CHL)*64);
  f32x4* dst4 = (f32x4*)dch;
  for(int i=threadIdx.x; i<CHL*4; i+=256){
    int t = i >> 2, q = i & 3;
    dst4[i] = src[t*16 + 8 + q];
  }
  float nA[DST];
  bool fast = load_nA(Alog, d, nA);
  float Es[DST];
  #pragma unroll
  for(int s=0;s<DST;s++) Es[s] = 0.f;
  float cumD = 0.f;
  __syncthreads();
  const ushort_t*  uu = u  + ((size_t)b*LEN + c*CHL)*DIN + d;
  const _Float16*  pd = dF + ((size_t)b*LEN + c*CHL)*DIN + d;
  if(fast){
    for(int t=0;t<CHL;++t){
      float dv = (float)pd[(size_t)t*DIN];
      float uv = bf2f(uu[(size_t)t*DIN]);
      float du = dv*uv;
      cumD += dv;
      float a1 = __expf(-dv);
      float av[DST];
      POW_CHAIN(av, a1);
      const f32x4* r4 = (const f32x4*)(dch + t*16);
      f32x4 B0=r4[0], B1=r4[1], B2=r4[2], B3=r4[3];
      Es[0]=av[0]*Es[0]+du*B0.x;  Es[1]=av[1]*Es[1]+du*B0.y;
      Es[2]=av[2]*Es[2]+du*B0.z;  Es[3]=av[3]*Es[3]+du*B0.w;
      Es[4]=av[4]*Es[4]+du*B1.x;  Es[5]=av[5]*Es[5]+du*B1.y;
      Es[6]=av[6]*Es[6]+du*B1.z;  Es[7]=av[7]*Es[7]+du*B1.w;
      Es[8]=av[8]*Es[8]+du*B2.x;  Es[9]=av[9]*Es[9]+du*B2.y;
      Es[10]=av[10]*Es[10]+du*B2.z; Es[11]=av[11]*Es[11]+du*B2.w;
      Es[12]=av[12]*Es[12]+du*B3.x; Es[13]=av[13]*Es[13]+du*B3.y;
      Es[14]=av[14]*Es[14]+du*B3.z; Es[15]=av[15]*Es[15]+du*B3.w;
    }
  } else {
    for(int t=0;t<CHL;++t){
      float dv = (float)pd[(size_t)t*DIN];
      float uv = bf2f(uu[(size_t)t*DIN]);
      float du = dv*uv;
      cumD += dv;
      const float* row = dch + t*16;
      #pragma unroll
      for(int s=0;s<DST;s++){
        float a = __expf(dv*nA[s]);
        Es[s] = a*Es[s] + du*row[s];
      }
    }
  }
  size_t o = (size_t)(b*NCH + c)*DST*DIN + d;
  #pragma unroll
  for(int s=0;s<DST;s++) E[o + (size_t)s*DIN] = Es[s];
  cum[(size_t)(b*NCH + c)*DIN + d] = cumD;
}

// ---------------- scan phase B: combine chunk boundaries; Hs in-place over E ----------------
__global__ __launch_bounds__(256) void scanB_k(const float* __restrict__ cum,
    const float* __restrict__ Alog, float* __restrict__ E){
  int g = blockIdx.x*256 + threadIdx.x;   // 65536 = Bsz*DST*DIN
  int d = g & 1023;
  int s = (g >> 10) & 15;
  int b = g >> 14;
  float v = -__expf(Alog[d*DST + s]);
  float tgt = -(float)(s+1);
  float nA = (fabsf(v - tgt) < 1e-4f*(float)(s+1)) ? tgt : v;
  float h = 0.f;
  for(int c=0;c<NCH;c++){
    float p = __expf(cum[(size_t)(b*NCH + c)*DIN + d] * nA);
    size_t o = (size_t)((b*NCH + c)*DST + s)*DIN + d;
    float e = E[o];
    E[o] = h;
    h = p*h + e;
  }
}

// ---------------- scan phase C: replay, y=(scan+u*D)*sz, y bf16 over u ----------------
__global__ __launch_bounds__(256,4) void scanC_k(ushort_t* __restrict__ u,
    const float* __restrict__ dbl, const float* __restrict__ Alog,
    const float* __restrict__ Hs, const float* __restrict__ Dp, const ushort_t* __restrict__ sz,
    const _Float16* __restrict__ dF){
  __shared__ __align__(16) float dch[CHL*32];   // B,C cols
  int bid = blockIdx.x;
  int c = bid & (NCH-1);
  int dblk = (bid >> 6) & 3;
  int b = bid >> 8;
  int d = dblk*256 + threadIdx.x;
  const f32x4* src = (const f32x4*)(dbl + ((size_t)b*LEN + c*CHL)*64);
  f32x4* dst4 = (f32x4*)dch;
  for(int i=threadIdx.x; i<CHL*8; i+=256){
    int t = i >> 3, q = i & 7;
    dst4[i] = src[t*16 + 8 + q];
  }
  float nA[DST];
  bool fast = load_nA(Alog, d, nA);
  float h[DST];
  size_t ho = (size_t)(b*NCH + c)*DST*DIN + d;
  #pragma unroll
  for(int s=0;s<DST;s++) h[s] = Hs[ho + (size_t)s*DIN];
  float Dv = Dp[d];
  __syncthreads();
  ushort_t* uu = u + ((size_t)b*LEN + c*CHL)*DIN + d;
  const ushort_t* zz = sz + ((size_t)b*LEN + c*CHL)*DIN + d;
  const _Float16* pd = dF + ((size_t)b*LEN + c*CHL)*DIN + d;
  if(fast){
    for(int t=0;t<CHL;++t){
      float dv = (float)pd[(size_t)t*DIN];
      float uv = bf2f(uu[(size_t)t*DIN]);
      float du = dv*uv;
      float a1 = __expf(-dv);
      float av[DST];
      POW_CHAIN(av, a1);
      const f32x4* r4 = (const f32x4*)(dch + t*32);
      f32x4 B0=r4[0], B1=r4[1], B2=r4[2], B3=r4[3];
      f32x4 C0=r4[4], C1=r4[5], C2=r4[6], C3=r4[7];
      float y0, y1, y2, y3;
      h[0]=av[0]*h[0]+du*B0.x;  h[1]=av[1]*h[1]+du*B0.y;
      h[2]=av[2]*h[2]+du*B0.z;  h[3]=av[3]*h[3]+du*B0.w;
      y0 = h[0]*C0.x + h[1]*C0.y; y1 = h[2]*C0.z + h[3]*C0.w;
      h[4]=av[4]*h[4]+du*B1.x;  h[5]=av[5]*h[5]+du*B1.y;
      h[6]=av[6]*h[6]+du*B1.z;  h[7]=av[7]*h[7]+du*B1.w;
      y2 = h[4]*C1.x + h[5]*C1.y; y3 = h[6]*C1.z + h[7]*C1.w;
      h[8]=av[8]*h[8]+du*B2.x;  h[9]=av[9]*h[9]+du*B2.y;
      h[10]=av[10]*h[10]+du*B2.z; h[11]=av[11]*h[11]+du*B2.w;
      y0 += h[8]*C2.x + h[9]*C2.y; y1 += h[10]*C2.z + h[11]*C2.w;
      h[12]=av[12]*h[12]+du*B3.x; h[13]=av[13]*h[13]+du*B3.y;
      h[14]=av[14]*h[14]+du*B3.z; h[15]=av[15]*h[15]+du*B3.w;
      y2 += h[12]*C3.x + h[13]*C3.y; y3 += h[14]*C3.z + h[15]*C3.w;
      float y = (y0+y1) + (y2+y3) + uv*Dv;
      y *= bf2f(zz[(size_t)t*DIN]);
      uu[(size_t)t*DIN] = f2bf(y);
    }
  } else {
    for(int t=0;t<CHL;++t){
      float dv = (float)pd[(size_t)t*DIN];
      float uv = bf2f(uu[(size_t)t*DIN]);
      float du = dv*uv;
      const float* row = dch + t*32;
      float y = 0.f;
      #pragma unroll
      for(int s=0;s<DST;s++){
        float a = __expf(dv*nA[s]);
        h[s] = a*h[s] + du*row[s];
        y += h[s]*row[16+s];
      }
      y += uv*Dv;
      y *= bf2f(zz[(size_t)t*DIN]);
      uu[(size_t)t*DIN] = f2bf(y);
    }
  }
}

// ---------------- GEMM4 MFMA v6 (best verified): dbuf gl2lds + counted vmcnt ----------------
// y[16384][1024] x Woutb[512][1024] -> out[b][n][l]
__global__ __launch_bounds__(256) void gemm4_mfma(const ushort_t* __restrict__ A,
    const ushort_t* __restrict__ Bw, float* __restrict__ out){
  __shared__ __align__(16) ushort_t smem[2*16384];   // 64 KiB; epilogue reuses as float
  int tid = threadIdx.x;
  int wave = tid >> 6, lane = tid & 63;
  // XCD-aware swizzle: 512 blocks, 8 XCDs -> 64 contiguous tiles per XCD
  int flat = blockIdx.y * 4 + blockIdx.x;
  int orig = (flat & 7) * 64 + (flat >> 3);
  int n0 = (orig & 3) * 128;       // N=512 -> 4
  int m0 = (orig >> 2) * 128;
  int wm = (wave >> 1) * 64, wn = (wave & 1) * 64;
  int lm = lane & 15;
  int lk = lane >> 4;
  int sx = lm & 7;
  f32x4 zero4 = {0.f,0.f,0.f,0.f};
  f32x4 acc[4][4];
  #pragma unroll
  for(int i=0;i<4;i++)
    #pragma unroll
    for(int j=0;j<4;j++) acc[i][j] = zero4;
  // prologue: stage t=0 into buf 0
  #pragma unroll
  for(int i=0;i<4;i++){
    int c = i*256 + tid, r = c >> 3, kc = c & 7;
    int kg = kc ^ (r & 7);
    gl2lds16(&A [(size_t)(m0 + r)*1024 + kg*8], &smem[c*8]);
    gl2lds16(&Bw[(size_t)(n0 + r)*1024 + kg*8], &smem[8192 + c*8]);
  }
  int cur = 0;
  for(int t=0; t<16; ++t){
    if(t < 15){
      int k0n = (t+1)*64;
      ushort_t* Ad = &smem[(cur^1)*16384];
      ushort_t* Bd = &smem[(cur^1)*16384 + 8192];
      #pragma unroll
      for(int i=0;i<4;i++){
        int c = i*256 + tid, r = c >> 3, kc = c & 7;
        int kg = kc ^ (r & 7);
        gl2lds16(&A [(size_t)(m0 + r)*1024 + k0n + kg*8], &Ad[c*8]);
        gl2lds16(&Bw[(size_t)(n0 + r)*1024 + k0n + kg*8], &Bd[c*8]);
      }
      asm volatile("s_waitcnt vmcnt(8)" ::: "memory");
    } else {
      asm volatile("s_waitcnt vmcnt(0)" ::: "memory");
    }
    __builtin_amdgcn_sched_barrier(0);
    __builtin_amdgcn_s_barrier();
    const ushort_t* As = &smem[cur*16384];
    const ushort_t* Bs = &smem[cur*16384 + 8192];
    #pragma unroll
    for(int kk=0; kk<64; kk+=32){
      short8 af[4], bf[4];
      int ch = ((kk >> 3) + lk) ^ sx;
      #pragma unroll
      for(int i=0;i<4;i++){
        af[i] = *(const short8*)&As[(wm + i*16 + lm)*64 + ch*8];
        bf[i] = *(const short8*)&Bs[(wn + i*16 + lm)*64 + ch*8];
      }
      #pragma unroll
      for(int i=0;i<4;i++)
        #pragma unroll
        for(int j=0;j<4;j++)
          acc[i][j] = __builtin_amdgcn_mfma_f32_16x16x32_bf16(af[i], bf[j], acc[i][j], 0, 0, 0);
    }
    __builtin_amdgcn_s_barrier();
    cur ^= 1;
  }
  // epilogue: LDS transpose, 32-n groups, coalesced float4 stores along l(=m)
  float* T = (float*)smem;               // [32][132] fp32 = 16,896 B
  int b = m0 >> 12, l0 = m0 & 4095;
  for(int g=0; g<4; ++g){
    __syncthreads();
    if((g >> 1) == (wave & 1)){
      int jg = g & 1;
      #pragma unroll
      for(int j2=0;j2<2;j2++){
        int j = jg*2 + j2;
        #pragma unroll
        for(int i=0;i<4;i++)
          #pragma unroll
          for(int r=0;r<4;r++){
            int ml = wm + i*16 + lk*4 + r;
            int nl = wn + j*16 + lm - g*32;
            T[nl*132 + ml] = acc[i][j][r];
          }
      }
    }
    __syncthreads();
    int nl = tid >> 3, seg = tid & 7;
    float* dst = &out[((size_t)b*DIM + n0 + g*32 + nl)*LEN + l0 + seg*16];
    #pragma unroll
    for(int k=0;k<4;k++){
      float4 v = *(const float4*)&T[nl*132 + seg*16 + k*4];
      *(float4*)&dst[k*4] = v;
    }
  }
}

extern "C" void kernel_launch(void* const* d_in, const int* in_sizes, int n_in,
                              void* d_out, int out_size, void* d_ws, size_t ws_size,
                              hipStream_t stream) {
  const float* x    = (const float*)d_in[0];
  const float* lnw  = (const float*)d_in[1];
  const float* lnb  = (const float*)d_in[2];
  const float* Win  = (const float*)d_in[3];
  const float* cw   = (const float*)d_in[4];
  const float* cb   = (const float*)d_in[5];
  const float* Wxp  = (const float*)d_in[6];
  const float* Wdt  = (const float*)d_in[7];
  const float* bdt  = (const float*)d_in[8];
  const float* Alog = (const float*)d_in[9];
  const float* Dp   = (const float*)d_in[10];
  const float* Wout = (const float*)d_in[11];
  float* out = (float*)d_out;
  float* ws  = (float*)d_ws;

  // workspace layout (float-slot offsets), total 147.25 MiB — no overlapping live ranges
  float*    mu   = ws;                          // 16384
  float*    rs   = ws + 16384;                  // 16384
  _Float16* xin  = (_Float16*)(ws + 32768);     // fp16, 16,777,216 halves (live gemm1..conv)
  _Float16* dF   = (_Float16*)(ws + 32768);     // same region, disjoint lifetime (deltag..scanC)
  float*    E    = ws + 32768 + 8388608;        // 4,194,304 fl (Hs in-place)
  float*    cum  = ws + 32768 + 12582912;       // 262,144 fl
  ushort_t* sz   = (ushort_t*)(ws + 32768 + 16777216);            // bf16 16,777,216
  ushort_t* u    = (ushort_t*)(ws + 32768 + 16777216 + 8388608);  // bf16 16,777,216 (y overwrites)
  ushort_t* xnT  = (ushort_t*)(ws + 32768 + 16777216 + 16777216); // bf16 8,388,608
  float*    dbl  = (float*)xnT;                 // alias after gemm1: 1,048,576 fp32
  ushort_t* Winb = (ushort_t*)(ws + 32768 + 16777216 + 16777216 + 4194304);
  ushort_t* Woutb= Winb + 1048576;
  ushort_t* Wxpb = Woutb + 524288;

  hipLaunchKernelGGL(prep_k,     dim3(1856),    dim3(1024), 0, stream, Win, Wout, Wxp, Winb, Woutb, Wxpb, x, mu, rs);
  hipLaunchKernelGGL(xnt_k,      dim3(2048),    dim3(256), 0, stream, x, mu, rs, lnw, lnb, xnT);
  hipLaunchKernelGGL(gemm1_mfma, dim3(16,128),  dim3(256), 0, stream, xnT, Winb, xin, sz);
  hipLaunchKernelGGL(conv_silu_k,dim3(1024),    dim3(256), 0, stream, xin, cw, cb, u);
  hipLaunchKernelGGL(gemm2_mfma, dim3(256),     dim3(256), 0, stream, u, Wxpb, dbl);
  hipLaunchKernelGGL(deltag_k,   dim3(1024),    dim3(256), 0, stream, dbl, Wdt, bdt, dF);
  hipLaunchKernelGGL(scanA_k,    dim3(1024),    dim3(256), 0, stream, u, dbl, Alog, dF, E, cum);
  hipLaunchKernelGGL(scanB_k,    dim3(256),     dim3(256), 0, stream, cum, Alog, E);
  hipLaunchKernelGGL(scanC_k,    dim3(1024),    dim3(256), 0, stream, u, dbl, Alog, E, Dp, sz, dF);
  hipLaunchKernelGGL(gemm4_mfma, dim3(4,128),   dim3(256), 0, stream, u, Woutb, out);
}